// Round 10
// baseline (536.153 us; speedup 1.0000x reference)
//
#include <hip/hip_runtime.h>

typedef __attribute__((ext_vector_type(4))) float f32x4;
typedef __attribute__((ext_vector_type(8))) short short8;
typedef __attribute__((ext_vector_type(4))) short short4v;

#define MFMA_B16(a,b,c) __builtin_amdgcn_mfma_f32_16x16x32_bf16((a),(b),(c),0,0,0)

static __device__ __forceinline__ unsigned short f2bf(float x){
  unsigned int u = __float_as_uint(x);
  u += 0x7fffu + ((u >> 16) & 1u);
  return (unsigned short)(u >> 16);
}

static __device__ __forceinline__ short8 pack8(f32x4 a, f32x4 b){
  short8 r;
  r[0]=(short)f2bf(a[0]); r[1]=(short)f2bf(a[1]); r[2]=(short)f2bf(a[2]); r[3]=(short)f2bf(a[3]);
  r[4]=(short)f2bf(b[0]); r[5]=(short)f2bf(b[1]); r[6]=(short)f2bf(b[2]); r[7]=(short)f2bf(b[3]);
  return r;
}

static __device__ __forceinline__ short4v pack4(const f32x4& a){
  short4v r;
  r[0]=(short)f2bf(a[0]); r[1]=(short)f2bf(a[1]); r[2]=(short)f2bf(a[2]); r[3]=(short)f2bf(a[3]);
  return r;
}

__global__ void prep_w(const float* __restrict__ ipw, const float* __restrict__ opw,
                       unsigned short* __restrict__ wbf){
  int i = blockIdx.x * 256 + threadIdx.x;
  float v = (i < 384*128) ? ipw[i] : opw[i - 384*128];
  wbf[i] = f2bf(v);
}

#define STR 136   // shorts per staged row (128 + 8 pad)

// ============================ group2 kernel ============================
// 256 threads, 2 heads/wave, TTP=7.  Transposes via per-wave LDS strips;
// Q and K use DISJOINT strip columns (Q at 0, K at 24) so the compiler can
// batch both writes then both reads (one roundtrip instead of two per tile).
// Packing is the PROVEN manual f2bf (R9's cvt_pk asm produced NaN — reverted).
template<int TTP>
__global__ __launch_bounds__(256, 2)
void fused_attn(const float* __restrict__ feat,
                const float* __restrict__ pos,
                const int* __restrict__ inds,
                int LW,
                const unsigned short* __restrict__ wqkv,   // bf16 [384][128]
                const unsigned short* __restrict__ wout,   // bf16 [128][128]
                const float* __restrict__ ipb, const float* __restrict__ opb,
                float* __restrict__ out)
{
  constexpr int PSTR = 16*(TTP+1) + 8;   // P/vT strip row length
  constexpr int STRT = 48;               // transpose strip: Q cols 0-15, K cols 24-39
  extern __shared__ __align__(16) unsigned short smem[];
  unsigned short* sQK = smem;                     // [16*TTP][STR] bf16 (f+pos)
  unsigned short* sF  = smem + 16*TTP*STR;        // [16*TTP][STR] bf16 f, reused for O
  unsigned short* sPb = smem + 2*16*TTP*STR;      // per-wave [16][PSTR] vT/P strips
  unsigned short* sTs = smem + 2*16*TTP*STR + 4*16*PSTR;  // per-wave [16][STRT]

  const int w = blockIdx.x;
  const int Lv = (w & 1) ? (LW >> 1) : LW;
  const int T  = (Lv + 15) >> 4;              // query/key tiles (<= TTP)
  const long ibase = (long)w * LW;
  const int tid = threadIdx.x;
  const int wv = tid >> 6, lane = tid & 63, c = lane & 15, q = lane >> 4;
  const short8 Z8 = {0,0,0,0,0,0,0,0};
  const f32x4  Z4 = {0.f,0.f,0.f,0.f};

  {
    const int rg = tid >> 4, ch = tid & 15;
    #pragma unroll
    for (int s = 0; s < TTP; ++s){
      if (s < T){
        const int row = s*16 + rg;
        short8 fv = Z8, qv = Z8;
        if (row < Lv){
          const int tok = inds[ibase + row];
          const float* fr = feat + (long)tok*128 + ch*8;
          const float* pr = pos + (ibase + row)*128 + ch*8;
          f32x4 f0 = *(const f32x4*)fr, f1 = *(const f32x4*)(fr+4);
          f32x4 p0 = *(const f32x4*)pr, p1 = *(const f32x4*)(pr+4);
          fv = pack8(f0, f1); qv = pack8(f0+p0, f1+p1);
        }
        *(short8*)&sF [row*STR + ch*8] = fv;
        *(short8*)&sQK[row*STR + ch*8] = qv;
      }
    }
  }
  __syncthreads();

  unsigned short* Pb = sPb + wv*16*PSTR;
  unsigned short* Ts = sTs + wv*16*STRT;
  if (T & 1){
    const short4v z4 = {0,0,0,0};
    *(short4v*)&Pb[c*PSTR + 16*T + 4*q] = z4;
  }
  short4v of[2][TTP];

  #pragma unroll
  for (int hh = 0; hh < 2; ++hh){
    const int h = wv*2 + hh;
    short8 bQ[4], bK[4], bV[4];
    const unsigned short* wr = wqkv + (h*16 + c)*128 + q*8;
    #pragma unroll
    for (int kk = 0; kk < 4; ++kk){
      bQ[kk] = *(const short8*)(wr + kk*32);
      bK[kk] = *(const short8*)(wr + kk*32 + 128*128);
      bV[kk] = *(const short8*)(wr + kk*32 + 2*128*128);
    }
    float bq_r[4], bk_r[4];
    #pragma unroll
    for (int r = 0; r < 4; ++r){
      bq_r[r] = ipb[h*16 + 4*q + r];
      bk_r[r] = ipb[128 + h*16 + 4*q + r];
    }
    const float bv_c = ipb[256 + h*16 + c];

    short8 qAf[TTP], kBf[TTP];

    #pragma unroll
    for (int t = 0; t < TTP; ++t) if (t < T){
      f32x4 qt = Z4, kt = Z4, vt = Z4;
      #pragma unroll
      for (int kk = 0; kk < 4; ++kk){
        const short8 aQ = *(const short8*)&sQK[(16*t + c)*STR + kk*32 + q*8];
        const short8 aF = *(const short8*)&sF [(16*t + c)*STR + kk*32 + q*8];
        qt = MFMA_B16(bQ[kk], aQ, qt);
        kt = MFMA_B16(bK[kk], aQ, kt);
        vt = MFMA_B16(aF, bV[kk], vt);
      }
      #pragma unroll
      for (int r = 0; r < 4; ++r){
        qt[r] = (qt[r] + bq_r[r]) * 0.25f;
        kt[r] += bk_r[r];
        const int key = 16*t + 4*q + r;
        vt[r] = (key < Lv) ? (vt[r] + bv_c) : 0.f;
      }
      *(short4v*)&Pb[c*PSTR + 16*t + 4*q] = pack4(vt);
      // Q and K writes to disjoint strip columns -> batched, one roundtrip
      *(short4v*)&Ts[c*STRT + 4*q]      = pack4(qt);
      *(short4v*)&Ts[c*STRT + 24 + 4*q] = pack4(kt);
      const short8 qf = *(const short8*)&Ts[c*STRT + q*8];
      const short8 kf = *(const short8*)&Ts[c*STRT + 24 + q*8];
      qAf[t] = (q < 2) ? qf : Z8;
      kBf[t] = (q < 2) ? kf : Z8;
    }

    short8 vBf[(TTP+1)/2];
    #pragma unroll
    for (int u = 0; u < (TTP+1)/2; ++u) if (u < ((T+1)>>1))
      vBf[u] = *(const short8*)&Pb[c*PSTR + 32*u + q*8];

    #pragma unroll
    for (int t = 0; t < TTP; ++t) if (t < T){
      f32x4 St[TTP];
      #pragma unroll
      for (int tk = 0; tk < TTP; ++tk) if (tk < T){
        St[tk] = MFMA_B16(kBf[tk], qAf[t], Z4);     // C [key][query] = S^T
        #pragma unroll
        for (int r = 0; r < 4; ++r){
          const int key = 16*tk + 4*q + r;
          if (key >= Lv) St[tk][r] = -1e30f;
        }
      }
      f32x4 mm = {-1e30f,-1e30f,-1e30f,-1e30f};
      #pragma unroll
      for (int tk = 0; tk < TTP; ++tk) if (tk < T){
        mm[0]=fmaxf(mm[0],St[tk][0]); mm[1]=fmaxf(mm[1],St[tk][1]);
        mm[2]=fmaxf(mm[2],St[tk][2]); mm[3]=fmaxf(mm[3],St[tk][3]);
      }
      float m = fmaxf(fmaxf(mm[0],mm[1]), fmaxf(mm[2],mm[3]));
      m = fmaxf(m, __shfl_xor(m, 16));
      m = fmaxf(m, __shfl_xor(m, 32));
      f32x4 ss = Z4;
      #pragma unroll
      for (int tk = 0; tk < TTP; ++tk) if (tk < T){
        #pragma unroll
        for (int r = 0; r < 4; ++r){
          float e = __expf(St[tk][r] - m);
          St[tk][r] = e; ss[r] += e;
        }
      }
      float sum = (ss[0]+ss[1]) + (ss[2]+ss[3]);
      sum += __shfl_xor(sum, 16);
      sum += __shfl_xor(sum, 32);
      const float inv = 1.0f / sum;
      #pragma unroll
      for (int tk = 0; tk < TTP; ++tk) if (tk < T){
        short4v p4;
        #pragma unroll
        for (int r = 0; r < 4; ++r) p4[r] = (short)f2bf(St[tk][r] * inv);
        *(short4v*)&Pb[c*PSTR + 16*tk + 4*q] = p4;
      }
      f32x4 o = Z4;
      #pragma unroll
      for (int u = 0; u < (TTP+1)/2; ++u) if (u < ((T+1)>>1)){
        const short8 ap = *(const short8*)&Pb[c*PSTR + 32*u + q*8];
        o = MFMA_B16(ap, vBf[u], o);
      }
      short4v ob;
      #pragma unroll
      for (int r = 0; r < 4; ++r) ob[r] = (short)f2bf(o[r]);
      of[hh][t] = ob;
    }
  } // hh

  __syncthreads();
  #pragma unroll
  for (int hh = 0; hh < 2; ++hh){
    const int h = wv*2 + hh;
    #pragma unroll
    for (int t = 0; t < TTP; ++t) if (t < T){
      #pragma unroll
      for (int r = 0; r < 4; ++r)
        sF[(16*t + 4*q + r)*STR + h*16 + c] = (unsigned short)of[hh][t][r];
    }
  }
  __syncthreads();

  float bo_r[8];
  #pragma unroll
  for (int ct = 0; ct < 8; ++ct) bo_r[ct] = opb[ct*16 + c];
  #pragma unroll
  for (int ti = 0; ti < 2; ++ti){
    const int t = wv + ti*4;
    if (t < T){
      f32x4 acc[8];
      #pragma unroll
      for (int ct = 0; ct < 8; ++ct) acc[ct] = Z4;
      #pragma unroll
      for (int p = 0; p < 4; ++p){
        const short8 ao = *(const short8*)&sF[(16*t + c)*STR + p*32 + q*8];
        #pragma unroll
        for (int ct = 0; ct < 8; ++ct){
          const short8 bw = *(const short8*)&wout[(ct*16 + c)*128 + p*32 + q*8];
          acc[ct] = MFMA_B16(ao, bw, acc[ct]);
        }
      }
      #pragma unroll
      for (int r = 0; r < 4; ++r){
        const int l = 16*t + 4*q + r;
        if (l < Lv){
          const int tok = inds[ibase + l];
          float* orow = out + (long)tok*128;
          #pragma unroll
          for (int ct = 0; ct < 8; ++ct)
            orow[ct*16 + c] = acc[ct][r] + bo_r[ct];
        }
      }
    }
  }
}

// ============================ group1 kernel ============================
// 512 threads = 8 waves covering TWO windows per block (R8 structure,
// UNCHANGED — manual f2bf packing).  LDS 76800 B -> 2 blocks/CU = 16 waves/CU.
#define TT3 3
#define PSTR3 (16*(TT3+1) + 8)   // 72
#define STRT3 24
#define HALF3 (2*48*STR + 4*16*PSTR3 + 4*16*STRT3)   // shorts per window half

__global__ __launch_bounds__(512, 4)
void fused_attn3_2w(const float* __restrict__ feat,
                    const float* __restrict__ pos,
                    const int* __restrict__ inds,
                    const unsigned short* __restrict__ wqkv,
                    const unsigned short* __restrict__ wout,
                    const float* __restrict__ ipb, const float* __restrict__ opb,
                    float* __restrict__ out)
{
  extern __shared__ __align__(16) unsigned short smem[];
  const int tid = threadIdx.x;
  const int wv8 = tid >> 6;                  // 0..7
  const int wh  = wv8 >> 2;                  // window half 0/1
  const int wv  = wv8 & 3;                   // wave within half
  const int lane = tid & 63, c = lane & 15, q = lane >> 4;

  unsigned short* base = smem + wh*HALF3;
  unsigned short* sQK = base;                     // [48][STR]
  unsigned short* sF  = base + 48*STR;            // [48][STR], O later
  unsigned short* sPb = base + 2*48*STR;          // 4 x [16][PSTR3]
  unsigned short* sTs = sPb + 4*16*PSTR3;         // 4 x [16][STRT3]

  const int w = blockIdx.x*2 + wh;
  const int LW = 36;
  const int Lv = wh ? 18 : 36;
  const int T  = wh ? 2 : 3;
  const long ibase = (long)w * LW;
  const short8 Z8 = {0,0,0,0,0,0,0,0};
  const f32x4  Z4 = {0.f,0.f,0.f,0.f};

  {
    const int ltid = tid & 255;
    const int rg = ltid >> 4, ch = ltid & 15;
    #pragma unroll
    for (int s = 0; s < TT3; ++s){
      if (s < T){
        const int row = s*16 + rg;
        short8 fv = Z8, qv = Z8;
        if (row < Lv){
          const int tok = inds[ibase + row];
          const float* fr = feat + (long)tok*128 + ch*8;
          const float* pr = pos + (ibase + row)*128 + ch*8;
          f32x4 f0 = *(const f32x4*)fr, f1 = *(const f32x4*)(fr+4);
          f32x4 p0 = *(const f32x4*)pr, p1 = *(const f32x4*)(pr+4);
          fv = pack8(f0, f1); qv = pack8(f0+p0, f1+p1);
        }
        *(short8*)&sF [row*STR + ch*8] = fv;
        *(short8*)&sQK[row*STR + ch*8] = qv;
      }
    }
  }
  __syncthreads();

  unsigned short* Pb = sPb + wv*16*PSTR3;
  unsigned short* Ts = sTs + wv*16*STRT3;
  if (T & 1){
    const short4v z4 = {0,0,0,0};
    *(short4v*)&Pb[c*PSTR3 + 16*T + 4*q] = z4;
  }
  short4v of[2][TT3];

  #pragma unroll
  for (int hh = 0; hh < 2; ++hh){
    const int h = wv*2 + hh;
    short8 bQ[4], bK[4], bV[4];
    const unsigned short* wr = wqkv + (h*16 + c)*128 + q*8;
    #pragma unroll
    for (int kk = 0; kk < 4; ++kk){
      bQ[kk] = *(const short8*)(wr + kk*32);
      bK[kk] = *(const short8*)(wr + kk*32 + 128*128);
      bV[kk] = *(const short8*)(wr + kk*32 + 2*128*128);
    }
    float bq_r[4], bk_r[4];
    #pragma unroll
    for (int r = 0; r < 4; ++r){
      bq_r[r] = ipb[h*16 + 4*q + r];
      bk_r[r] = ipb[128 + h*16 + 4*q + r];
    }
    const float bv_c = ipb[256 + h*16 + c];

    short8 qAf[TT3], kBf[TT3];

    #pragma unroll
    for (int t = 0; t < TT3; ++t) if (t < T){
      f32x4 qt = Z4, kt = Z4, vt = Z4;
      #pragma unroll
      for (int kk = 0; kk < 4; ++kk){
        const short8 aQ = *(const short8*)&sQK[(16*t + c)*STR + kk*32 + q*8];
        const short8 aF = *(const short8*)&sF [(16*t + c)*STR + kk*32 + q*8];
        qt = MFMA_B16(bQ[kk], aQ, qt);
        kt = MFMA_B16(bK[kk], aQ, kt);
        vt = MFMA_B16(aF, bV[kk], vt);
      }
      #pragma unroll
      for (int r = 0; r < 4; ++r){
        qt[r] = (qt[r] + bq_r[r]) * 0.25f;
        kt[r] += bk_r[r];
        const int key = 16*t + 4*q + r;
        vt[r] = (key < Lv) ? (vt[r] + bv_c) : 0.f;
      }
      *(short4v*)&Pb[c*PSTR3 + 16*t + 4*q] = pack4(vt);
      *(short4v*)&Ts[c*STRT3 + 4*q] = pack4(qt);
      const short8 qf = *(const short8*)&Ts[c*STRT3 + q*8];
      qAf[t] = (q < 2) ? qf : Z8;
      *(short4v*)&Ts[c*STRT3 + 4*q] = pack4(kt);
      const short8 kf = *(const short8*)&Ts[c*STRT3 + q*8];
      kBf[t] = (q < 2) ? kf : Z8;
    }

    short8 vBf[2];
    #pragma unroll
    for (int u = 0; u < 2; ++u) if (u < ((T+1)>>1))
      vBf[u] = *(const short8*)&Pb[c*PSTR3 + 32*u + q*8];

    #pragma unroll
    for (int t = 0; t < TT3; ++t) if (t < T){
      f32x4 St[TT3];
      #pragma unroll
      for (int tk = 0; tk < TT3; ++tk) if (tk < T){
        St[tk] = MFMA_B16(kBf[tk], qAf[t], Z4);     // C [key][query] = S^T
        #pragma unroll
        for (int r = 0; r < 4; ++r){
          const int key = 16*tk + 4*q + r;
          if (key >= Lv) St[tk][r] = -1e30f;
        }
      }
      f32x4 mm = {-1e30f,-1e30f,-1e30f,-1e30f};
      #pragma unroll
      for (int tk = 0; tk < TT3; ++tk) if (tk < T){
        mm[0]=fmaxf(mm[0],St[tk][0]); mm[1]=fmaxf(mm[1],St[tk][1]);
        mm[2]=fmaxf(mm[2],St[tk][2]); mm[3]=fmaxf(mm[3],St[tk][3]);
      }
      float m = fmaxf(fmaxf(mm[0],mm[1]), fmaxf(mm[2],mm[3]));
      m = fmaxf(m, __shfl_xor(m, 16));
      m = fmaxf(m, __shfl_xor(m, 32));
      f32x4 ss = Z4;
      #pragma unroll
      for (int tk = 0; tk < TT3; ++tk) if (tk < T){
        #pragma unroll
        for (int r = 0; r < 4; ++r){
          float e = __expf(St[tk][r] - m);
          St[tk][r] = e; ss[r] += e;
        }
      }
      float sum = (ss[0]+ss[1]) + (ss[2]+ss[3]);
      sum += __shfl_xor(sum, 16);
      sum += __shfl_xor(sum, 32);
      const float inv = 1.0f / sum;
      #pragma unroll
      for (int tk = 0; tk < TT3; ++tk) if (tk < T){
        short4v p4;
        #pragma unroll
        for (int r = 0; r < 4; ++r) p4[r] = (short)f2bf(St[tk][r] * inv);
        *(short4v*)&Pb[c*PSTR3 + 16*tk + 4*q] = p4;
      }
      f32x4 o = Z4;
      #pragma unroll
      for (int u = 0; u < 2; ++u) if (u < ((T+1)>>1)){
        const short8 ap = *(const short8*)&Pb[c*PSTR3 + 32*u + q*8];
        o = MFMA_B16(ap, vBf[u], o);
      }
      short4v ob;
      #pragma unroll
      for (int r = 0; r < 4; ++r) ob[r] = (short)f2bf(o[r]);
      of[hh][t] = ob;
    }
  } // hh

  __syncthreads();   // all waves done reading sQK/sF (both halves)
  #pragma unroll
  for (int hh = 0; hh < 2; ++hh){
    const int h = wv*2 + hh;
    #pragma unroll
    for (int t = 0; t < TT3; ++t) if (t < T){
      #pragma unroll
      for (int r = 0; r < 4; ++r)
        sF[(16*t + 4*q + r)*STR + h*16 + c] = (unsigned short)of[hh][t][r];
    }
  }
  __syncthreads();   // O complete

  // ---- out projection: wave handles query tile wv of its window
  {
    const int t = wv;
    if (t < T){
      float bo_r[8];
      #pragma unroll
      for (int ct = 0; ct < 8; ++ct) bo_r[ct] = opb[ct*16 + c];
      f32x4 acc[8];
      #pragma unroll
      for (int ct = 0; ct < 8; ++ct) acc[ct] = Z4;
      #pragma unroll
      for (int p = 0; p < 4; ++p){
        const short8 ao = *(const short8*)&sF[(16*t + c)*STR + p*32 + q*8];
        #pragma unroll
        for (int ct = 0; ct < 8; ++ct){
          const short8 bw = *(const short8*)&wout[(ct*16 + c)*128 + p*32 + q*8];
          acc[ct] = MFMA_B16(ao, bw, acc[ct]);
        }
      }
      #pragma unroll
      for (int r = 0; r < 4; ++r){
        const int l = 16*t + 4*q + r;
        if (l < Lv){
          const int tok = inds[ibase + l];
          float* orow = out + (long)tok*128;
          #pragma unroll
          for (int ct = 0; ct < 8; ++ct)
            orow[ct*16 + c] = acc[ct][r] + bo_r[ct];
        }
      }
    }
  }
}

extern "C" void kernel_launch(void* const* d_in, const int* in_sizes, int n_in,
                              void* d_out, int out_size, void* d_ws, size_t ws_size,
                              hipStream_t stream) {
  const float* feat = (const float*)d_in[0];
  const float* pos1 = (const float*)d_in[1];
  const float* pos2 = (const float*)d_in[2];
  const float* ipw  = (const float*)d_in[3];
  const float* ipb  = (const float*)d_in[4];
  const float* opw  = (const float*)d_in[5];
  const float* opb  = (const float*)d_in[6];
  const int*   inds1 = (const int*)d_in[7];
  const int*   inds2 = (const int*)d_in[8];
  float* out = (float*)d_out;
  unsigned short* wbf = (unsigned short*)d_ws;   // 384*128 + 128*128 bf16
  unsigned short* wob = wbf + 384*128;

  prep_w<<<dim3(256), dim3(256), 0, stream>>>(ipw, opw, wbf);

  // group2 (L=100): TTP=7, 256 threads.
  // LDS = (2*112*136 + 4*16*136 + 4*16*48)*2 = 84480 B.
  {
    const int lds2 = (2*112*STR + 4*16*(16*8 + 8) + 4*16*48) * 2;
    hipFuncSetAttribute((const void*)fused_attn<7>,
                        hipFuncAttributeMaxDynamicSharedMemorySize, lds2);
    fused_attn<7><<<dim3(1024), dim3(256), lds2, stream>>>(
        feat, pos2, inds2, 100, wbf, wob, ipb, opb, out);
  }
  // group1 (L=36): 512 threads, 2 windows/block, 2048 blocks.
  // LDS = 2*HALF3*2 = 76800 B -> 2 blocks/CU = 16 waves/CU.
  {
    const int lds1 = 2*HALF3*2;
    hipFuncSetAttribute((const void*)fused_attn3_2w,
                        hipFuncAttributeMaxDynamicSharedMemorySize, lds1);
    fused_attn3_2w<<<dim3(2048), dim3(512), lds1, stream>>>(
        feat, pos1, inds1, wbf, wob, ipb, opb, out);
  }
}

// Round 11
// 467.554 us; speedup vs baseline: 1.1467x; 1.1467x over previous
//
#include <hip/hip_runtime.h>

typedef __attribute__((ext_vector_type(4))) float f32x4;
typedef __attribute__((ext_vector_type(8))) short short8;
typedef __attribute__((ext_vector_type(4))) short short4v;

#define MFMA_B16(a,b,c) __builtin_amdgcn_mfma_f32_16x16x32_bf16((a),(b),(c),0,0,0)

static __device__ __forceinline__ unsigned short f2bf(float x){
  unsigned int u = __float_as_uint(x);
  u += 0x7fffu + ((u >> 16) & 1u);
  return (unsigned short)(u >> 16);
}

static __device__ __forceinline__ short8 pack8(f32x4 a, f32x4 b){
  short8 r;
  r[0]=(short)f2bf(a[0]); r[1]=(short)f2bf(a[1]); r[2]=(short)f2bf(a[2]); r[3]=(short)f2bf(a[3]);
  r[4]=(short)f2bf(b[0]); r[5]=(short)f2bf(b[1]); r[6]=(short)f2bf(b[2]); r[7]=(short)f2bf(b[3]);
  return r;
}

static __device__ __forceinline__ short4v pack4(const f32x4& a){
  short4v r;
  r[0]=(short)f2bf(a[0]); r[1]=(short)f2bf(a[1]); r[2]=(short)f2bf(a[2]); r[3]=(short)f2bf(a[3]);
  return r;
}

__global__ void prep_w(const float* __restrict__ ipw, const float* __restrict__ opw,
                       unsigned short* __restrict__ wbf){
  int i = blockIdx.x * 256 + threadIdx.x;
  float v = (i < 384*128) ? ipw[i] : opw[i - 384*128];
  wbf[i] = f2bf(v);
}

#define STR 136   // shorts per staged row (128 + 8 pad)

// ============================ group2 kernel ============================
// 256 threads, 2 heads/wave, TTP=7.  Q transpose via Ts strip; K transpose
// via the Pb strip's key-tail block (cols 16*TTP..16*TTP+15), which is dead
// during projection.  Both writes precede both reads -> ONE lgkmcnt roundtrip
// per tile instead of two.  The tail block is re-zeroed after each head's
// projection (satisfies the PV/vBf zero-tail requirement).  LDS = 81408 B
// -> 2 blocks/CU (R10's widened-strip variant hit 84480 -> 1 block/CU, -48%).
template<int TTP>
__global__ __launch_bounds__(256, 2)
void fused_attn(const float* __restrict__ feat,
                const float* __restrict__ pos,
                const int* __restrict__ inds,
                int LW,
                const unsigned short* __restrict__ wqkv,   // bf16 [384][128]
                const unsigned short* __restrict__ wout,   // bf16 [128][128]
                const float* __restrict__ ipb, const float* __restrict__ opb,
                float* __restrict__ out)
{
  constexpr int PSTR = 16*(TTP+1) + 8;   // P/vT strip row length
  constexpr int STRT = 24;               // Q transpose strip row length
  constexpr int KOFF = 16*TTP;           // K transpose block inside Pb (tail cols)
  extern __shared__ __align__(16) unsigned short smem[];
  unsigned short* sQK = smem;                     // [16*TTP][STR] bf16 (f+pos)
  unsigned short* sF  = smem + 16*TTP*STR;        // [16*TTP][STR] bf16 f, reused for O
  unsigned short* sPb = smem + 2*16*TTP*STR;      // per-wave [16][PSTR] vT/P strips
  unsigned short* sTs = smem + 2*16*TTP*STR + 4*16*PSTR;  // per-wave [16][STRT]

  const int w = blockIdx.x;
  const int Lv = (w & 1) ? (LW >> 1) : LW;
  const int T  = (Lv + 15) >> 4;              // query/key tiles (<= TTP)
  const long ibase = (long)w * LW;
  const int tid = threadIdx.x;
  const int wv = tid >> 6, lane = tid & 63, c = lane & 15, q = lane >> 4;
  const short8 Z8 = {0,0,0,0,0,0,0,0};
  const f32x4  Z4 = {0.f,0.f,0.f,0.f};

  {
    const int rg = tid >> 4, ch = tid & 15;
    #pragma unroll
    for (int s = 0; s < TTP; ++s){
      if (s < T){
        const int row = s*16 + rg;
        short8 fv = Z8, qv = Z8;
        if (row < Lv){
          const int tok = inds[ibase + row];
          const float* fr = feat + (long)tok*128 + ch*8;
          const float* pr = pos + (ibase + row)*128 + ch*8;
          f32x4 f0 = *(const f32x4*)fr, f1 = *(const f32x4*)(fr+4);
          f32x4 p0 = *(const f32x4*)pr, p1 = *(const f32x4*)(pr+4);
          fv = pack8(f0, f1); qv = pack8(f0+p0, f1+p1);
        }
        *(short8*)&sF [row*STR + ch*8] = fv;
        *(short8*)&sQK[row*STR + ch*8] = qv;
      }
    }
  }
  __syncthreads();

  unsigned short* Pb = sPb + wv*16*PSTR;
  unsigned short* Ts = sTs + wv*16*STRT;
  short4v of[2][TTP];

  #pragma unroll
  for (int hh = 0; hh < 2; ++hh){
    const int h = wv*2 + hh;
    short8 bQ[4], bK[4], bV[4];
    const unsigned short* wr = wqkv + (h*16 + c)*128 + q*8;
    #pragma unroll
    for (int kk = 0; kk < 4; ++kk){
      bQ[kk] = *(const short8*)(wr + kk*32);
      bK[kk] = *(const short8*)(wr + kk*32 + 128*128);
      bV[kk] = *(const short8*)(wr + kk*32 + 2*128*128);
    }
    float bq_r[4], bk_r[4];
    #pragma unroll
    for (int r = 0; r < 4; ++r){
      bq_r[r] = ipb[h*16 + 4*q + r];
      bk_r[r] = ipb[128 + h*16 + 4*q + r];
    }
    const float bv_c = ipb[256 + h*16 + c];

    short8 qAf[TTP], kBf[TTP];

    #pragma unroll
    for (int t = 0; t < TTP; ++t) if (t < T){
      f32x4 qt = Z4, kt = Z4, vt = Z4;
      #pragma unroll
      for (int kk = 0; kk < 4; ++kk){
        const short8 aQ = *(const short8*)&sQK[(16*t + c)*STR + kk*32 + q*8];
        const short8 aF = *(const short8*)&sF [(16*t + c)*STR + kk*32 + q*8];
        qt = MFMA_B16(bQ[kk], aQ, qt);
        kt = MFMA_B16(bK[kk], aQ, kt);
        vt = MFMA_B16(aF, bV[kk], vt);
      }
      #pragma unroll
      for (int r = 0; r < 4; ++r){
        qt[r] = (qt[r] + bq_r[r]) * 0.25f;
        kt[r] += bk_r[r];
        const int key = 16*t + 4*q + r;
        vt[r] = (key < Lv) ? (vt[r] + bv_c) : 0.f;
      }
      // V tile -> vT strip; Q -> Ts; K -> Pb tail block.  All three writes
      // hit disjoint addresses, so both reads sit behind ONE roundtrip wait.
      *(short4v*)&Pb[c*PSTR + 16*t + 4*q]   = pack4(vt);
      *(short4v*)&Ts[c*STRT + 4*q]          = pack4(qt);
      *(short4v*)&Pb[c*PSTR + KOFF + 4*q]   = pack4(kt);
      const short8 qf = *(const short8*)&Ts[c*STRT + q*8];
      const short8 kf = *(const short8*)&Pb[c*PSTR + KOFF + q*8];
      qAf[t] = (q < 2) ? qf : Z8;
      kBf[t] = (q < 2) ? kf : Z8;
    }
    // Re-zero the K/tail block: PV's A-frag and vBf read the 32-key group
    // covering tile T when T is odd; it must decode as 0.0 there.
    {
      const short4v z4 = {0,0,0,0};
      *(short4v*)&Pb[c*PSTR + KOFF + 4*q] = z4;
    }

    short8 vBf[(TTP+1)/2];
    #pragma unroll
    for (int u = 0; u < (TTP+1)/2; ++u) if (u < ((T+1)>>1))
      vBf[u] = *(const short8*)&Pb[c*PSTR + 32*u + q*8];

    #pragma unroll
    for (int t = 0; t < TTP; ++t) if (t < T){
      f32x4 St[TTP];
      #pragma unroll
      for (int tk = 0; tk < TTP; ++tk) if (tk < T){
        St[tk] = MFMA_B16(kBf[tk], qAf[t], Z4);     // C [key][query] = S^T
        #pragma unroll
        for (int r = 0; r < 4; ++r){
          const int key = 16*tk + 4*q + r;
          if (key >= Lv) St[tk][r] = -1e30f;
        }
      }
      f32x4 mm = {-1e30f,-1e30f,-1e30f,-1e30f};
      #pragma unroll
      for (int tk = 0; tk < TTP; ++tk) if (tk < T){
        mm[0]=fmaxf(mm[0],St[tk][0]); mm[1]=fmaxf(mm[1],St[tk][1]);
        mm[2]=fmaxf(mm[2],St[tk][2]); mm[3]=fmaxf(mm[3],St[tk][3]);
      }
      float m = fmaxf(fmaxf(mm[0],mm[1]), fmaxf(mm[2],mm[3]));
      m = fmaxf(m, __shfl_xor(m, 16));
      m = fmaxf(m, __shfl_xor(m, 32));
      f32x4 ss = Z4;
      #pragma unroll
      for (int tk = 0; tk < TTP; ++tk) if (tk < T){
        #pragma unroll
        for (int r = 0; r < 4; ++r){
          float e = __expf(St[tk][r] - m);
          St[tk][r] = e; ss[r] += e;
        }
      }
      float sum = (ss[0]+ss[1]) + (ss[2]+ss[3]);
      sum += __shfl_xor(sum, 16);
      sum += __shfl_xor(sum, 32);
      const float inv = 1.0f / sum;
      #pragma unroll
      for (int tk = 0; tk < TTP; ++tk) if (tk < T){
        short4v p4;
        #pragma unroll
        for (int r = 0; r < 4; ++r) p4[r] = (short)f2bf(St[tk][r] * inv);
        *(short4v*)&Pb[c*PSTR + 16*tk + 4*q] = p4;
      }
      f32x4 o = Z4;
      #pragma unroll
      for (int u = 0; u < (TTP+1)/2; ++u) if (u < ((T+1)>>1)){
        const short8 ap = *(const short8*)&Pb[c*PSTR + 32*u + q*8];
        o = MFMA_B16(ap, vBf[u], o);
      }
      short4v ob;
      #pragma unroll
      for (int r = 0; r < 4; ++r) ob[r] = (short)f2bf(o[r]);
      of[hh][t] = ob;
    }
  } // hh

  __syncthreads();
  #pragma unroll
  for (int hh = 0; hh < 2; ++hh){
    const int h = wv*2 + hh;
    #pragma unroll
    for (int t = 0; t < TTP; ++t) if (t < T){
      #pragma unroll
      for (int r = 0; r < 4; ++r)
        sF[(16*t + 4*q + r)*STR + h*16 + c] = (unsigned short)of[hh][t][r];
    }
  }
  __syncthreads();

  float bo_r[8];
  #pragma unroll
  for (int ct = 0; ct < 8; ++ct) bo_r[ct] = opb[ct*16 + c];
  #pragma unroll
  for (int ti = 0; ti < 2; ++ti){
    const int t = wv + ti*4;
    if (t < T){
      f32x4 acc[8];
      #pragma unroll
      for (int ct = 0; ct < 8; ++ct) acc[ct] = Z4;
      #pragma unroll
      for (int p = 0; p < 4; ++p){
        const short8 ao = *(const short8*)&sF[(16*t + c)*STR + p*32 + q*8];
        #pragma unroll
        for (int ct = 0; ct < 8; ++ct){
          const short8 bw = *(const short8*)&wout[(ct*16 + c)*128 + p*32 + q*8];
          acc[ct] = MFMA_B16(ao, bw, acc[ct]);
        }
      }
      #pragma unroll
      for (int r = 0; r < 4; ++r){
        const int l = 16*t + 4*q + r;
        if (l < Lv){
          const int tok = inds[ibase + l];
          float* orow = out + (long)tok*128;
          #pragma unroll
          for (int ct = 0; ct < 8; ++ct)
            orow[ct*16 + c] = acc[ct][r] + bo_r[ct];
        }
      }
    }
  }
}

// ============================ group1 kernel ============================
// 512 threads = 8 waves covering TWO windows per block (R8 structure) with
// the same Q-via-Ts / K-via-Pb-tail single-roundtrip scheme.
// LDS 76800 B -> 2 blocks/CU = 16 waves/CU.
#define TT3 3
#define PSTR3 (16*(TT3+1) + 8)   // 72
#define STRT3 24
#define KOFF3 (16*TT3)           // 48
#define HALF3 (2*48*STR + 4*16*PSTR3 + 4*16*STRT3)   // shorts per window half

__global__ __launch_bounds__(512, 4)
void fused_attn3_2w(const float* __restrict__ feat,
                    const float* __restrict__ pos,
                    const int* __restrict__ inds,
                    const unsigned short* __restrict__ wqkv,
                    const unsigned short* __restrict__ wout,
                    const float* __restrict__ ipb, const float* __restrict__ opb,
                    float* __restrict__ out)
{
  extern __shared__ __align__(16) unsigned short smem[];
  const int tid = threadIdx.x;
  const int wv8 = tid >> 6;                  // 0..7
  const int wh  = wv8 >> 2;                  // window half 0/1
  const int wv  = wv8 & 3;                   // wave within half
  const int lane = tid & 63, c = lane & 15, q = lane >> 4;

  unsigned short* base = smem + wh*HALF3;
  unsigned short* sQK = base;                     // [48][STR]
  unsigned short* sF  = base + 48*STR;            // [48][STR], O later
  unsigned short* sPb = base + 2*48*STR;          // 4 x [16][PSTR3]
  unsigned short* sTs = sPb + 4*16*PSTR3;         // 4 x [16][STRT3]

  const int w = blockIdx.x*2 + wh;
  const int LW = 36;
  const int Lv = wh ? 18 : 36;
  const int T  = wh ? 2 : 3;
  const long ibase = (long)w * LW;
  const short8 Z8 = {0,0,0,0,0,0,0,0};
  const f32x4  Z4 = {0.f,0.f,0.f,0.f};

  {
    const int ltid = tid & 255;
    const int rg = ltid >> 4, ch = ltid & 15;
    #pragma unroll
    for (int s = 0; s < TT3; ++s){
      if (s < T){
        const int row = s*16 + rg;
        short8 fv = Z8, qv = Z8;
        if (row < Lv){
          const int tok = inds[ibase + row];
          const float* fr = feat + (long)tok*128 + ch*8;
          const float* pr = pos + (ibase + row)*128 + ch*8;
          f32x4 f0 = *(const f32x4*)fr, f1 = *(const f32x4*)(fr+4);
          f32x4 p0 = *(const f32x4*)pr, p1 = *(const f32x4*)(pr+4);
          fv = pack8(f0, f1); qv = pack8(f0+p0, f1+p1);
        }
        *(short8*)&sF [row*STR + ch*8] = fv;
        *(short8*)&sQK[row*STR + ch*8] = qv;
      }
    }
  }
  __syncthreads();

  unsigned short* Pb = sPb + wv*16*PSTR3;
  unsigned short* Ts = sTs + wv*16*STRT3;
  short4v of[2][TT3];

  #pragma unroll
  for (int hh = 0; hh < 2; ++hh){
    const int h = wv*2 + hh;
    short8 bQ[4], bK[4], bV[4];
    const unsigned short* wr = wqkv + (h*16 + c)*128 + q*8;
    #pragma unroll
    for (int kk = 0; kk < 4; ++kk){
      bQ[kk] = *(const short8*)(wr + kk*32);
      bK[kk] = *(const short8*)(wr + kk*32 + 128*128);
      bV[kk] = *(const short8*)(wr + kk*32 + 2*128*128);
    }
    float bq_r[4], bk_r[4];
    #pragma unroll
    for (int r = 0; r < 4; ++r){
      bq_r[r] = ipb[h*16 + 4*q + r];
      bk_r[r] = ipb[128 + h*16 + 4*q + r];
    }
    const float bv_c = ipb[256 + h*16 + c];

    short8 qAf[TT3], kBf[TT3];

    #pragma unroll
    for (int t = 0; t < TT3; ++t) if (t < T){
      f32x4 qt = Z4, kt = Z4, vt = Z4;
      #pragma unroll
      for (int kk = 0; kk < 4; ++kk){
        const short8 aQ = *(const short8*)&sQK[(16*t + c)*STR + kk*32 + q*8];
        const short8 aF = *(const short8*)&sF [(16*t + c)*STR + kk*32 + q*8];
        qt = MFMA_B16(bQ[kk], aQ, qt);
        kt = MFMA_B16(bK[kk], aQ, kt);
        vt = MFMA_B16(aF, bV[kk], vt);
      }
      #pragma unroll
      for (int r = 0; r < 4; ++r){
        qt[r] = (qt[r] + bq_r[r]) * 0.25f;
        kt[r] += bk_r[r];
        const int key = 16*t + 4*q + r;
        vt[r] = (key < Lv) ? (vt[r] + bv_c) : 0.f;
      }
      *(short4v*)&Pb[c*PSTR3 + 16*t + 4*q]   = pack4(vt);
      *(short4v*)&Ts[c*STRT3 + 4*q]          = pack4(qt);
      *(short4v*)&Pb[c*PSTR3 + KOFF3 + 4*q]  = pack4(kt);
      const short8 qf = *(const short8*)&Ts[c*STRT3 + q*8];
      const short8 kf = *(const short8*)&Pb[c*PSTR3 + KOFF3 + q*8];
      qAf[t] = (q < 2) ? qf : Z8;
      kBf[t] = (q < 2) ? kf : Z8;
    }
    {
      const short4v z4 = {0,0,0,0};
      *(short4v*)&Pb[c*PSTR3 + KOFF3 + 4*q] = z4;
    }

    short8 vBf[2];
    #pragma unroll
    for (int u = 0; u < 2; ++u) if (u < ((T+1)>>1))
      vBf[u] = *(const short8*)&Pb[c*PSTR3 + 32*u + q*8];

    #pragma unroll
    for (int t = 0; t < TT3; ++t) if (t < T){
      f32x4 St[TT3];
      #pragma unroll
      for (int tk = 0; tk < TT3; ++tk) if (tk < T){
        St[tk] = MFMA_B16(kBf[tk], qAf[t], Z4);     // C [key][query] = S^T
        #pragma unroll
        for (int r = 0; r < 4; ++r){
          const int key = 16*tk + 4*q + r;
          if (key >= Lv) St[tk][r] = -1e30f;
        }
      }
      f32x4 mm = {-1e30f,-1e30f,-1e30f,-1e30f};
      #pragma unroll
      for (int tk = 0; tk < TT3; ++tk) if (tk < T){
        mm[0]=fmaxf(mm[0],St[tk][0]); mm[1]=fmaxf(mm[1],St[tk][1]);
        mm[2]=fmaxf(mm[2],St[tk][2]); mm[3]=fmaxf(mm[3],St[tk][3]);
      }
      float m = fmaxf(fmaxf(mm[0],mm[1]), fmaxf(mm[2],mm[3]));
      m = fmaxf(m, __shfl_xor(m, 16));
      m = fmaxf(m, __shfl_xor(m, 32));
      f32x4 ss = Z4;
      #pragma unroll
      for (int tk = 0; tk < TT3; ++tk) if (tk < T){
        #pragma unroll
        for (int r = 0; r < 4; ++r){
          float e = __expf(St[tk][r] - m);
          St[tk][r] = e; ss[r] += e;
        }
      }
      float sum = (ss[0]+ss[1]) + (ss[2]+ss[3]);
      sum += __shfl_xor(sum, 16);
      sum += __shfl_xor(sum, 32);
      const float inv = 1.0f / sum;
      #pragma unroll
      for (int tk = 0; tk < TT3; ++tk) if (tk < T){
        short4v p4;
        #pragma unroll
        for (int r = 0; r < 4; ++r) p4[r] = (short)f2bf(St[tk][r] * inv);
        *(short4v*)&Pb[c*PSTR3 + 16*tk + 4*q] = p4;
      }
      f32x4 o = Z4;
      #pragma unroll
      for (int u = 0; u < 2; ++u) if (u < ((T+1)>>1)){
        const short8 ap = *(const short8*)&Pb[c*PSTR3 + 32*u + q*8];
        o = MFMA_B16(ap, vBf[u], o);
      }
      short4v ob;
      #pragma unroll
      for (int r = 0; r < 4; ++r) ob[r] = (short)f2bf(o[r]);
      of[hh][t] = ob;
    }
  } // hh

  __syncthreads();   // all waves done reading sQK/sF (both halves)
  #pragma unroll
  for (int hh = 0; hh < 2; ++hh){
    const int h = wv*2 + hh;
    #pragma unroll
    for (int t = 0; t < TT3; ++t) if (t < T){
      #pragma unroll
      for (int r = 0; r < 4; ++r)
        sF[(16*t + 4*q + r)*STR + h*16 + c] = (unsigned short)of[hh][t][r];
    }
  }
  __syncthreads();   // O complete

  // ---- out projection: wave handles query tile wv of its window
  {
    const int t = wv;
    if (t < T){
      float bo_r[8];
      #pragma unroll
      for (int ct = 0; ct < 8; ++ct) bo_r[ct] = opb[ct*16 + c];
      f32x4 acc[8];
      #pragma unroll
      for (int ct = 0; ct < 8; ++ct) acc[ct] = Z4;
      #pragma unroll
      for (int p = 0; p < 4; ++p){
        const short8 ao = *(const short8*)&sF[(16*t + c)*STR + p*32 + q*8];
        #pragma unroll
        for (int ct = 0; ct < 8; ++ct){
          const short8 bw = *(const short8*)&wout[(ct*16 + c)*128 + p*32 + q*8];
          acc[ct] = MFMA_B16(ao, bw, acc[ct]);
        }
      }
      #pragma unroll
      for (int r = 0; r < 4; ++r){
        const int l = 16*t + 4*q + r;
        if (l < Lv){
          const int tok = inds[ibase + l];
          float* orow = out + (long)tok*128;
          #pragma unroll
          for (int ct = 0; ct < 8; ++ct)
            orow[ct*16 + c] = acc[ct][r] + bo_r[ct];
        }
      }
    }
  }
}

extern "C" void kernel_launch(void* const* d_in, const int* in_sizes, int n_in,
                              void* d_out, int out_size, void* d_ws, size_t ws_size,
                              hipStream_t stream) {
  const float* feat = (const float*)d_in[0];
  const float* pos1 = (const float*)d_in[1];
  const float* pos2 = (const float*)d_in[2];
  const float* ipw  = (const float*)d_in[3];
  const float* ipb  = (const float*)d_in[4];
  const float* opw  = (const float*)d_in[5];
  const float* opb  = (const float*)d_in[6];
  const int*   inds1 = (const int*)d_in[7];
  const int*   inds2 = (const int*)d_in[8];
  float* out = (float*)d_out;
  unsigned short* wbf = (unsigned short*)d_ws;   // 384*128 + 128*128 bf16
  unsigned short* wob = wbf + 384*128;

  prep_w<<<dim3(256), dim3(256), 0, stream>>>(ipw, opw, wbf);

  // group2 (L=100): TTP=7, 256 threads.
  // LDS = (2*112*136 + 4*16*136 + 4*16*24)*2 = 81408 B -> 2 blocks/CU.
  {
    const int lds2 = (2*112*STR + 4*16*(16*8 + 8) + 4*16*24) * 2;
    hipFuncSetAttribute((const void*)fused_attn<7>,
                        hipFuncAttributeMaxDynamicSharedMemorySize, lds2);
    fused_attn<7><<<dim3(1024), dim3(256), lds2, stream>>>(
        feat, pos2, inds2, 100, wbf, wob, ipb, opb, out);
  }
  // group1 (L=36): 512 threads, 2 windows/block, 2048 blocks.
  // LDS = 2*HALF3*2 = 76800 B -> 2 blocks/CU = 16 waves/CU.
  {
    const int lds1 = 2*HALF3*2;
    hipFuncSetAttribute((const void*)fused_attn3_2w,
                        hipFuncAttributeMaxDynamicSharedMemorySize, lds1);
    fused_attn3_2w<<<dim3(2048), dim3(512), lds1, stream>>>(
        feat, pos1, inds1, wbf, wob, ipb, opb, out);
  }
}

// Round 12
// 435.015 us; speedup vs baseline: 1.2325x; 1.0748x over previous
//
#include <hip/hip_runtime.h>

typedef __attribute__((ext_vector_type(4))) float f32x4;
typedef __attribute__((ext_vector_type(8))) short short8;
typedef __attribute__((ext_vector_type(4))) short short4v;

#define MFMA_B16(a,b,c) __builtin_amdgcn_mfma_f32_16x16x32_bf16((a),(b),(c),0,0,0)

static __device__ __forceinline__ unsigned short f2bf(float x){
  unsigned int u = __float_as_uint(x);
  u += 0x7fffu + ((u >> 16) & 1u);
  return (unsigned short)(u >> 16);
}

static __device__ __forceinline__ short8 pack8(f32x4 a, f32x4 b){
  short8 r;
  r[0]=(short)f2bf(a[0]); r[1]=(short)f2bf(a[1]); r[2]=(short)f2bf(a[2]); r[3]=(short)f2bf(a[3]);
  r[4]=(short)f2bf(b[0]); r[5]=(short)f2bf(b[1]); r[6]=(short)f2bf(b[2]); r[7]=(short)f2bf(b[3]);
  return r;
}

static __device__ __forceinline__ short4v pack4(const f32x4& a){
  short4v r;
  r[0]=(short)f2bf(a[0]); r[1]=(short)f2bf(a[1]); r[2]=(short)f2bf(a[2]); r[3]=(short)f2bf(a[3]);
  return r;
}

__global__ void prep_w(const float* __restrict__ ipw, const float* __restrict__ opw,
                       unsigned short* __restrict__ wbf){
  int i = blockIdx.x * 256 + threadIdx.x;
  float v = (i < 384*128) ? ipw[i] : opw[i - 384*128];
  wbf[i] = f2bf(v);
}

#define STR 136    // shorts per staged row (128 + 8 pad)

// group2 geometry (TTP=7)
#define PSTR2 (16*8 + 8)   // 136
#define STRT2 24
#define KOFF2 (16*7)       // 112

// group1 geometry (TT3=3)
#define TT3 3
#define PSTR3 (16*(TT3+1) + 8)   // 72
#define STRT3 24
#define KOFF3 (16*TT3)           // 48
#define HALF3 (2*48*STR + 4*16*PSTR3 + 4*16*STRT3)   // shorts per window half

// =============================== merged kernel ===============================
// ONE launch, 512 threads, 3072 blocks:
//   blocks [0,1024):    group2 window w=b (L=100).  All 8 waves stage (4 sweeps)
//                       and out-project (1 tile/wave); waves 0-3 run the proven
//                       2-head attention body (R11) unchanged.
//   blocks [1024,3072): group1 window PAIR (R11's fused_attn3_2w body verbatim).
// LDS request = g2 layout = 81408 B -> 2 blocks/CU for BOTH paths (g1 uses 76800).
// Merging removes the g2->g1 dispatch drain and mixes 4-wave g2 blocks with
// 8-wave g1 blocks on each CU for better latency hiding.
__global__ __launch_bounds__(512, 4)
void fused_all(const float* __restrict__ feat,
               const float* __restrict__ pos1, const float* __restrict__ pos2,
               const int* __restrict__ inds1, const int* __restrict__ inds2,
               const unsigned short* __restrict__ wqkv,
               const unsigned short* __restrict__ wout,
               const float* __restrict__ ipb, const float* __restrict__ opb,
               float* __restrict__ out)
{
  extern __shared__ __align__(16) unsigned short smem[];
  const int b  = blockIdx.x;
  const int tid = threadIdx.x;
  const short8 Z8 = {0,0,0,0,0,0,0,0};
  const f32x4  Z4 = {0.f,0.f,0.f,0.f};

  if (b < 1024){
    // ============================ group2 path ============================
    unsigned short* sQK = smem;                     // [112][STR]
    unsigned short* sF  = smem + 112*STR;           // [112][STR], O later
    unsigned short* sPb = smem + 2*112*STR;         // 4 x [16][PSTR2]
    unsigned short* sTs = sPb + 4*16*PSTR2;         // 4 x [16][STRT2]

    const int w  = b;
    const int Lv = (w & 1) ? 50 : 100;
    const int T  = (Lv + 15) >> 4;                  // 7 or 4
    const long ibase = (long)w * 100;
    const int wv4 = tid >> 6, lane = tid & 63, c = lane & 15, q = lane >> 4;

    // ---- staging: all 512 threads, 32 rows x 16 chunks per sweep (4 sweeps)
    {
      const int rg = tid >> 4, ch = tid & 15;       // rg 0..31
      #pragma unroll
      for (int s = 0; s < 4; ++s){
        const int row = s*32 + rg;
        if (row < 16*T){
          short8 fv = Z8, qv = Z8;
          if (row < Lv){
            const int tok = inds2[ibase + row];
            const float* fr = feat + (long)tok*128 + ch*8;
            const float* pr = pos2 + (ibase + row)*128 + ch*8;
            f32x4 f0 = *(const f32x4*)fr, f1 = *(const f32x4*)(fr+4);
            f32x4 p0 = *(const f32x4*)pr, p1 = *(const f32x4*)(pr+4);
            fv = pack8(f0, f1); qv = pack8(f0+p0, f1+p1);
          }
          *(short8*)&sF [row*STR + ch*8] = fv;
          *(short8*)&sQK[row*STR + ch*8] = qv;
        }
      }
    }
    __syncthreads();

    short4v of[2][7];
    if (wv4 < 4){
      const int wv = wv4;
      unsigned short* Pb = sPb + wv*16*PSTR2;
      unsigned short* Ts = sTs + wv*16*STRT2;

      #pragma unroll
      for (int hh = 0; hh < 2; ++hh){
        const int h = wv*2 + hh;
        short8 bQ[4], bK[4], bV[4];
        const unsigned short* wr = wqkv + (h*16 + c)*128 + q*8;
        #pragma unroll
        for (int kk = 0; kk < 4; ++kk){
          bQ[kk] = *(const short8*)(wr + kk*32);
          bK[kk] = *(const short8*)(wr + kk*32 + 128*128);
          bV[kk] = *(const short8*)(wr + kk*32 + 2*128*128);
        }
        float bq_r[4], bk_r[4];
        #pragma unroll
        for (int r = 0; r < 4; ++r){
          bq_r[r] = ipb[h*16 + 4*q + r];
          bk_r[r] = ipb[128 + h*16 + 4*q + r];
        }
        const float bv_c = ipb[256 + h*16 + c];

        short8 qAf[7], kBf[7];

        #pragma unroll
        for (int t = 0; t < 7; ++t) if (t < T){
          f32x4 qt = Z4, kt = Z4, vt = Z4;
          #pragma unroll
          for (int kk = 0; kk < 4; ++kk){
            const short8 aQ = *(const short8*)&sQK[(16*t + c)*STR + kk*32 + q*8];
            const short8 aF = *(const short8*)&sF [(16*t + c)*STR + kk*32 + q*8];
            qt = MFMA_B16(bQ[kk], aQ, qt);
            kt = MFMA_B16(bK[kk], aQ, kt);
            vt = MFMA_B16(aF, bV[kk], vt);
          }
          #pragma unroll
          for (int r = 0; r < 4; ++r){
            qt[r] = (qt[r] + bq_r[r]) * 0.25f;
            kt[r] += bk_r[r];
            const int key = 16*t + 4*q + r;
            vt[r] = (key < Lv) ? (vt[r] + bv_c) : 0.f;
          }
          *(short4v*)&Pb[c*PSTR2 + 16*t + 4*q]   = pack4(vt);
          *(short4v*)&Ts[c*STRT2 + 4*q]          = pack4(qt);
          *(short4v*)&Pb[c*PSTR2 + KOFF2 + 4*q]  = pack4(kt);
          const short8 qf = *(const short8*)&Ts[c*STRT2 + q*8];
          const short8 kf = *(const short8*)&Pb[c*PSTR2 + KOFF2 + q*8];
          qAf[t] = (q < 2) ? qf : Z8;
          kBf[t] = (q < 2) ? kf : Z8;
        }
        {
          const short4v z4 = {0,0,0,0};
          *(short4v*)&Pb[c*PSTR2 + KOFF2 + 4*q] = z4;
        }

        short8 vBf[4];
        #pragma unroll
        for (int u = 0; u < 4; ++u) if (u < ((T+1)>>1))
          vBf[u] = *(const short8*)&Pb[c*PSTR2 + 32*u + q*8];

        #pragma unroll
        for (int t = 0; t < 7; ++t) if (t < T){
          f32x4 St[7];
          #pragma unroll
          for (int tk = 0; tk < 7; ++tk) if (tk < T){
            St[tk] = MFMA_B16(kBf[tk], qAf[t], Z4);     // C [key][query] = S^T
            #pragma unroll
            for (int r = 0; r < 4; ++r){
              const int key = 16*tk + 4*q + r;
              if (key >= Lv) St[tk][r] = -1e30f;
            }
          }
          f32x4 mm = {-1e30f,-1e30f,-1e30f,-1e30f};
          #pragma unroll
          for (int tk = 0; tk < 7; ++tk) if (tk < T){
            mm[0]=fmaxf(mm[0],St[tk][0]); mm[1]=fmaxf(mm[1],St[tk][1]);
            mm[2]=fmaxf(mm[2],St[tk][2]); mm[3]=fmaxf(mm[3],St[tk][3]);
          }
          float m = fmaxf(fmaxf(mm[0],mm[1]), fmaxf(mm[2],mm[3]));
          m = fmaxf(m, __shfl_xor(m, 16));
          m = fmaxf(m, __shfl_xor(m, 32));
          f32x4 ss = Z4;
          #pragma unroll
          for (int tk = 0; tk < 7; ++tk) if (tk < T){
            #pragma unroll
            for (int r = 0; r < 4; ++r){
              float e = __expf(St[tk][r] - m);
              St[tk][r] = e; ss[r] += e;
            }
          }
          float sum = (ss[0]+ss[1]) + (ss[2]+ss[3]);
          sum += __shfl_xor(sum, 16);
          sum += __shfl_xor(sum, 32);
          const float inv = 1.0f / sum;
          #pragma unroll
          for (int tk = 0; tk < 7; ++tk) if (tk < T){
            short4v p4;
            #pragma unroll
            for (int r = 0; r < 4; ++r) p4[r] = (short)f2bf(St[tk][r] * inv);
            *(short4v*)&Pb[c*PSTR2 + 16*tk + 4*q] = p4;
          }
          f32x4 o = Z4;
          #pragma unroll
          for (int u = 0; u < 4; ++u) if (u < ((T+1)>>1)){
            const short8 ap = *(const short8*)&Pb[c*PSTR2 + 32*u + q*8];
            o = MFMA_B16(ap, vBf[u], o);
          }
          short4v ob;
          #pragma unroll
          for (int r = 0; r < 4; ++r) ob[r] = (short)f2bf(o[r]);
          of[hh][t] = ob;
        }
      } // hh
    } // wv4 < 4

    __syncthreads();   // attention done; sQK/sF free
    if (wv4 < 4){
      const int wv = wv4;
      #pragma unroll
      for (int hh = 0; hh < 2; ++hh){
        const int h = wv*2 + hh;
        #pragma unroll
        for (int t = 0; t < 7; ++t) if (t < T){
          #pragma unroll
          for (int r = 0; r < 4; ++r)
            sF[(16*t + 4*q + r)*STR + h*16 + c] = (unsigned short)of[hh][t][r];
        }
      }
    }
    __syncthreads();   // O complete

    // ---- out projection: wave wv4 handles tile t = wv4 (waves 0..T-1 active)
    {
      const int t = wv4;
      if (t < T){
        float bo_r[8];
        #pragma unroll
        for (int ct = 0; ct < 8; ++ct) bo_r[ct] = opb[ct*16 + c];
        f32x4 acc[8];
        #pragma unroll
        for (int ct = 0; ct < 8; ++ct) acc[ct] = Z4;
        #pragma unroll
        for (int p = 0; p < 4; ++p){
          const short8 ao = *(const short8*)&sF[(16*t + c)*STR + p*32 + q*8];
          #pragma unroll
          for (int ct = 0; ct < 8; ++ct){
            const short8 bw = *(const short8*)&wout[(ct*16 + c)*128 + p*32 + q*8];
            acc[ct] = MFMA_B16(ao, bw, acc[ct]);
          }
        }
        #pragma unroll
        for (int r = 0; r < 4; ++r){
          const int l = 16*t + 4*q + r;
          if (l < Lv){
            const int tok = inds2[ibase + l];
            float* orow = out + (long)tok*128;
            #pragma unroll
            for (int ct = 0; ct < 8; ++ct)
              orow[ct*16 + c] = acc[ct][r] + bo_r[ct];
          }
        }
      }
    }
  } else {
    // ============================ group1 path ============================
    // (R11 fused_attn3_2w body, verbatim; uses first 76800 B of LDS)
    const int wv8 = tid >> 6;                  // 0..7
    const int wh  = wv8 >> 2;                  // window half 0/1
    const int wv  = wv8 & 3;                   // wave within half
    const int lane = tid & 63, c = lane & 15, q = lane >> 4;

    unsigned short* base = smem + wh*HALF3;
    unsigned short* sQK = base;                     // [48][STR]
    unsigned short* sF  = base + 48*STR;            // [48][STR], O later
    unsigned short* sPb = base + 2*48*STR;          // 4 x [16][PSTR3]
    unsigned short* sTs = sPb + 4*16*PSTR3;         // 4 x [16][STRT3]

    const int w = (b - 1024)*2 + wh;
    const int LW = 36;
    const int Lv = wh ? 18 : 36;
    const int T  = wh ? 2 : 3;
    const long ibase = (long)w * LW;

    {
      const int ltid = tid & 255;
      const int rg = ltid >> 4, ch = ltid & 15;
      #pragma unroll
      for (int s = 0; s < TT3; ++s){
        if (s < T){
          const int row = s*16 + rg;
          short8 fv = Z8, qv = Z8;
          if (row < Lv){
            const int tok = inds1[ibase + row];
            const float* fr = feat + (long)tok*128 + ch*8;
            const float* pr = pos1 + (ibase + row)*128 + ch*8;
            f32x4 f0 = *(const f32x4*)fr, f1 = *(const f32x4*)(fr+4);
            f32x4 p0 = *(const f32x4*)pr, p1 = *(const f32x4*)(pr+4);
            fv = pack8(f0, f1); qv = pack8(f0+p0, f1+p1);
          }
          *(short8*)&sF [row*STR + ch*8] = fv;
          *(short8*)&sQK[row*STR + ch*8] = qv;
        }
      }
    }
    __syncthreads();

    unsigned short* Pb = sPb + wv*16*PSTR3;
    unsigned short* Ts = sTs + wv*16*STRT3;
    short4v of[2][TT3];

    #pragma unroll
    for (int hh = 0; hh < 2; ++hh){
      const int h = wv*2 + hh;
      short8 bQ[4], bK[4], bV[4];
      const unsigned short* wr = wqkv + (h*16 + c)*128 + q*8;
      #pragma unroll
      for (int kk = 0; kk < 4; ++kk){
        bQ[kk] = *(const short8*)(wr + kk*32);
        bK[kk] = *(const short8*)(wr + kk*32 + 128*128);
        bV[kk] = *(const short8*)(wr + kk*32 + 2*128*128);
      }
      float bq_r[4], bk_r[4];
      #pragma unroll
      for (int r = 0; r < 4; ++r){
        bq_r[r] = ipb[h*16 + 4*q + r];
        bk_r[r] = ipb[128 + h*16 + 4*q + r];
      }
      const float bv_c = ipb[256 + h*16 + c];

      short8 qAf[TT3], kBf[TT3];

      #pragma unroll
      for (int t = 0; t < TT3; ++t) if (t < T){
        f32x4 qt = Z4, kt = Z4, vt = Z4;
        #pragma unroll
        for (int kk = 0; kk < 4; ++kk){
          const short8 aQ = *(const short8*)&sQK[(16*t + c)*STR + kk*32 + q*8];
          const short8 aF = *(const short8*)&sF [(16*t + c)*STR + kk*32 + q*8];
          qt = MFMA_B16(bQ[kk], aQ, qt);
          kt = MFMA_B16(bK[kk], aQ, kt);
          vt = MFMA_B16(aF, bV[kk], vt);
        }
        #pragma unroll
        for (int r = 0; r < 4; ++r){
          qt[r] = (qt[r] + bq_r[r]) * 0.25f;
          kt[r] += bk_r[r];
          const int key = 16*t + 4*q + r;
          vt[r] = (key < Lv) ? (vt[r] + bv_c) : 0.f;
        }
        *(short4v*)&Pb[c*PSTR3 + 16*t + 4*q]   = pack4(vt);
        *(short4v*)&Ts[c*STRT3 + 4*q]          = pack4(qt);
        *(short4v*)&Pb[c*PSTR3 + KOFF3 + 4*q]  = pack4(kt);
        const short8 qf = *(const short8*)&Ts[c*STRT3 + q*8];
        const short8 kf = *(const short8*)&Pb[c*PSTR3 + KOFF3 + q*8];
        qAf[t] = (q < 2) ? qf : Z8;
        kBf[t] = (q < 2) ? kf : Z8;
      }
      {
        const short4v z4 = {0,0,0,0};
        *(short4v*)&Pb[c*PSTR3 + KOFF3 + 4*q] = z4;
      }

      short8 vBf[2];
      #pragma unroll
      for (int u = 0; u < 2; ++u) if (u < ((T+1)>>1))
        vBf[u] = *(const short8*)&Pb[c*PSTR3 + 32*u + q*8];

      #pragma unroll
      for (int t = 0; t < TT3; ++t) if (t < T){
        f32x4 St[TT3];
        #pragma unroll
        for (int tk = 0; tk < TT3; ++tk) if (tk < T){
          St[tk] = MFMA_B16(kBf[tk], qAf[t], Z4);     // C [key][query] = S^T
          #pragma unroll
          for (int r = 0; r < 4; ++r){
            const int key = 16*tk + 4*q + r;
            if (key >= Lv) St[tk][r] = -1e30f;
          }
        }
        f32x4 mm = {-1e30f,-1e30f,-1e30f,-1e30f};
        #pragma unroll
        for (int tk = 0; tk < TT3; ++tk) if (tk < T){
          mm[0]=fmaxf(mm[0],St[tk][0]); mm[1]=fmaxf(mm[1],St[tk][1]);
          mm[2]=fmaxf(mm[2],St[tk][2]); mm[3]=fmaxf(mm[3],St[tk][3]);
        }
        float m = fmaxf(fmaxf(mm[0],mm[1]), fmaxf(mm[2],mm[3]));
        m = fmaxf(m, __shfl_xor(m, 16));
        m = fmaxf(m, __shfl_xor(m, 32));
        f32x4 ss = Z4;
        #pragma unroll
        for (int tk = 0; tk < TT3; ++tk) if (tk < T){
          #pragma unroll
          for (int r = 0; r < 4; ++r){
            float e = __expf(St[tk][r] - m);
            St[tk][r] = e; ss[r] += e;
          }
        }
        float sum = (ss[0]+ss[1]) + (ss[2]+ss[3]);
        sum += __shfl_xor(sum, 16);
        sum += __shfl_xor(sum, 32);
        const float inv = 1.0f / sum;
        #pragma unroll
        for (int tk = 0; tk < TT3; ++tk) if (tk < T){
          short4v p4;
          #pragma unroll
          for (int r = 0; r < 4; ++r) p4[r] = (short)f2bf(St[tk][r] * inv);
          *(short4v*)&Pb[c*PSTR3 + 16*tk + 4*q] = p4;
        }
        f32x4 o = Z4;
        #pragma unroll
        for (int u = 0; u < 2; ++u) if (u < ((T+1)>>1)){
          const short8 ap = *(const short8*)&Pb[c*PSTR3 + 32*u + q*8];
          o = MFMA_B16(ap, vBf[u], o);
        }
        short4v ob;
        #pragma unroll
        for (int r = 0; r < 4; ++r) ob[r] = (short)f2bf(o[r]);
        of[hh][t] = ob;
      }
    } // hh

    __syncthreads();   // all waves done reading sQK/sF (both halves)
    #pragma unroll
    for (int hh = 0; hh < 2; ++hh){
      const int h = wv*2 + hh;
      #pragma unroll
      for (int t = 0; t < TT3; ++t) if (t < T){
        #pragma unroll
        for (int r = 0; r < 4; ++r)
          sF[(16*t + 4*q + r)*STR + h*16 + c] = (unsigned short)of[hh][t][r];
      }
    }
    __syncthreads();   // O complete

    // ---- out projection: wave handles query tile wv of its window
    {
      const int t = wv;
      if (t < T){
        float bo_r[8];
        #pragma unroll
        for (int ct = 0; ct < 8; ++ct) bo_r[ct] = opb[ct*16 + c];
        f32x4 acc[8];
        #pragma unroll
        for (int ct = 0; ct < 8; ++ct) acc[ct] = Z4;
        #pragma unroll
        for (int p = 0; p < 4; ++p){
          const short8 ao = *(const short8*)&sF[(16*t + c)*STR + p*32 + q*8];
          #pragma unroll
          for (int ct = 0; ct < 8; ++ct){
            const short8 bw = *(const short8*)&wout[(ct*16 + c)*128 + p*32 + q*8];
            acc[ct] = MFMA_B16(ao, bw, acc[ct]);
          }
        }
        #pragma unroll
        for (int r = 0; r < 4; ++r){
          const int l = 16*t + 4*q + r;
          if (l < Lv){
            const int tok = inds1[ibase + l];
            float* orow = out + (long)tok*128;
            #pragma unroll
            for (int ct = 0; ct < 8; ++ct)
              orow[ct*16 + c] = acc[ct][r] + bo_r[ct];
          }
        }
      }
    }
  }
}

extern "C" void kernel_launch(void* const* d_in, const int* in_sizes, int n_in,
                              void* d_out, int out_size, void* d_ws, size_t ws_size,
                              hipStream_t stream) {
  const float* feat = (const float*)d_in[0];
  const float* pos1 = (const float*)d_in[1];
  const float* pos2 = (const float*)d_in[2];
  const float* ipw  = (const float*)d_in[3];
  const float* ipb  = (const float*)d_in[4];
  const float* opw  = (const float*)d_in[5];
  const float* opb  = (const float*)d_in[6];
  const int*   inds1 = (const int*)d_in[7];
  const int*   inds2 = (const int*)d_in[8];
  float* out = (float*)d_out;
  unsigned short* wbf = (unsigned short*)d_ws;   // 384*128 + 128*128 bf16
  unsigned short* wob = wbf + 384*128;

  prep_w<<<dim3(256), dim3(256), 0, stream>>>(ipw, opw, wbf);

  // merged: LDS = g2 layout = (2*112*136 + 4*16*136 + 4*16*24)*2 = 81408 B
  // -> 2 blocks/CU (81408*2 = 162816 <= 163840).  g1 blocks use 76800 of it.
  const int lds = (2*112*STR + 4*16*PSTR2 + 4*16*STRT2) * 2;
  hipFuncSetAttribute((const void*)fused_all,
                      hipFuncAttributeMaxDynamicSharedMemorySize, lds);
  fused_all<<<dim3(1024 + 2048), dim3(512), lds, stream>>>(
      feat, pos1, pos2, inds1, inds2, wbf, wob, ipb, opb, out);
}

// Round 13
// 404.997 us; speedup vs baseline: 1.3238x; 1.0741x over previous
//
#include <hip/hip_runtime.h>

typedef __attribute__((ext_vector_type(4))) float f32x4;
typedef __attribute__((ext_vector_type(8))) short short8;
typedef __attribute__((ext_vector_type(4))) short short4v;

#define MFMA_B16(a,b,c) __builtin_amdgcn_mfma_f32_16x16x32_bf16((a),(b),(c),0,0,0)

static __device__ __forceinline__ unsigned short f2bf(float x){
  unsigned int u = __float_as_uint(x);
  u += 0x7fffu + ((u >> 16) & 1u);
  return (unsigned short)(u >> 16);
}

static __device__ __forceinline__ short8 pack8(f32x4 a, f32x4 b){
  short8 r;
  r[0]=(short)f2bf(a[0]); r[1]=(short)f2bf(a[1]); r[2]=(short)f2bf(a[2]); r[3]=(short)f2bf(a[3]);
  r[4]=(short)f2bf(b[0]); r[5]=(short)f2bf(b[1]); r[6]=(short)f2bf(b[2]); r[7]=(short)f2bf(b[3]);
  return r;
}

static __device__ __forceinline__ short4v pack4(const f32x4& a){
  short4v r;
  r[0]=(short)f2bf(a[0]); r[1]=(short)f2bf(a[1]); r[2]=(short)f2bf(a[2]); r[3]=(short)f2bf(a[3]);
  return r;
}

__global__ void prep_w(const float* __restrict__ ipw, const float* __restrict__ opw,
                       unsigned short* __restrict__ wbf){
  int i = blockIdx.x * 256 + threadIdx.x;
  float v = (i < 384*128) ? ipw[i] : opw[i - 384*128];
  wbf[i] = f2bf(v);
}

#define STR 136    // shorts per staged row (128 + 8 pad)

// group2 geometry (TTP=7), 1 head per wave
#define PSTR2 (16*8 + 8)   // 136
#define STRT2 24

// group1 geometry (TT3=3)
#define TT3 3
#define PSTR3 (16*(TT3+1) + 8)   // 72
#define STRT3 24
#define KOFF3 (16*TT3)           // 48
#define HALF3 (2*48*STR + 4*16*PSTR3 + 4*16*STRT3)   // shorts per window half

// =============================== merged kernel ===============================
// ONE launch, 512 threads, 3072 blocks:
//   blocks [0,1024):    group2 window (L=100), ONE head per wave (8 waves).
//     Phase A: Q,K projection (reads sQK) -> barrier (sQK dead).
//     Phase B: V projection (reads sF only); per-wave V^T/P strips OVERLAY the
//     dead sQK region (7 strips fit exactly; wave 7 uses a small annex).
//     1-head state peaks ~117 VGPR < 128 -> no spill under (512,4).
//   blocks [1024,3072): group1 window PAIR (R12 body verbatim, ~96 VGPR).
// LDS request = g1's 76800 B (g2 uses 71424) -> 2 blocks/CU for both paths.
__global__ __launch_bounds__(512, 4)
void fused_all(const float* __restrict__ feat,
               const float* __restrict__ pos1, const float* __restrict__ pos2,
               const int* __restrict__ inds1, const int* __restrict__ inds2,
               const unsigned short* __restrict__ wqkv,
               const unsigned short* __restrict__ wout,
               const float* __restrict__ ipb, const float* __restrict__ opb,
               float* __restrict__ out)
{
  extern __shared__ __align__(16) unsigned short smem[];
  const int b  = blockIdx.x;
  const int tid = threadIdx.x;
  const short8 Z8 = {0,0,0,0,0,0,0,0};
  const f32x4  Z4 = {0.f,0.f,0.f,0.f};

  if (b < 1024){
    // ============================ group2 path ============================
    unsigned short* sQK = smem;                     // [112][STR]; Pb overlay later
    unsigned short* sF  = smem + 112*STR;           // [112][STR]; O buffer later
    unsigned short* sTs = smem + 2*112*STR;         // 8 x [16][STRT2]
    unsigned short* sPx = sTs + 8*16*STRT2;         // wave 7's Pb annex [16][PSTR2]

    const int w  = b;
    const int Lv = (w & 1) ? 50 : 100;
    const int T  = (Lv + 15) >> 4;                  // 7 or 4
    const long ibase = (long)w * 100;
    const int wv8 = tid >> 6, lane = tid & 63, c = lane & 15, q = lane >> 4;

    // ---- staging: all 512 threads, 32 rows x 16 chunks per sweep (4 sweeps)
    {
      const int rg = tid >> 4, ch = tid & 15;       // rg 0..31
      #pragma unroll
      for (int s = 0; s < 4; ++s){
        const int row = s*32 + rg;
        if (row < 16*T){
          short8 fv = Z8, qv = Z8;
          if (row < Lv){
            const int tok = inds2[ibase + row];
            const float* fr = feat + (long)tok*128 + ch*8;
            const float* pr = pos2 + (ibase + row)*128 + ch*8;
            f32x4 f0 = *(const f32x4*)fr, f1 = *(const f32x4*)(fr+4);
            f32x4 p0 = *(const f32x4*)pr, p1 = *(const f32x4*)(pr+4);
            fv = pack8(f0, f1); qv = pack8(f0+p0, f1+p1);
          }
          *(short8*)&sF [row*STR + ch*8] = fv;
          *(short8*)&sQK[row*STR + ch*8] = qv;
        }
      }
    }
    __syncthreads();

    const int h = wv8;                              // one head per wave
    unsigned short* Ts = sTs + wv8*16*STRT2;
    short8 qAf[7], kBf[7];

    // ---- phase A: Q,K projection (reads sQK)
    {
      short8 bQ[4], bK[4];
      const unsigned short* wr = wqkv + (h*16 + c)*128 + q*8;
      #pragma unroll
      for (int kk = 0; kk < 4; ++kk){
        bQ[kk] = *(const short8*)(wr + kk*32);
        bK[kk] = *(const short8*)(wr + kk*32 + 128*128);
      }
      float bq_r[4], bk_r[4];
      #pragma unroll
      for (int r = 0; r < 4; ++r){
        bq_r[r] = ipb[h*16 + 4*q + r];
        bk_r[r] = ipb[128 + h*16 + 4*q + r];
      }
      #pragma unroll
      for (int t = 0; t < 7; ++t) if (t < T){
        f32x4 qt = Z4, kt = Z4;
        #pragma unroll
        for (int kk = 0; kk < 4; ++kk){
          const short8 aQ = *(const short8*)&sQK[(16*t + c)*STR + kk*32 + q*8];
          qt = MFMA_B16(bQ[kk], aQ, qt);
          kt = MFMA_B16(bK[kk], aQ, kt);
        }
        #pragma unroll
        for (int r = 0; r < 4; ++r){
          qt[r] = (qt[r] + bq_r[r]) * 0.25f;
          kt[r] += bk_r[r];
        }
        *(short4v*)&Ts[c*STRT2 + 4*q] = pack4(qt);
        const short8 qf = *(const short8*)&Ts[c*STRT2 + q*8];
        qAf[t] = (q < 2) ? qf : Z8;
        *(short4v*)&Ts[c*STRT2 + 4*q] = pack4(kt);
        const short8 kf = *(const short8*)&Ts[c*STRT2 + q*8];
        kBf[t] = (q < 2) ? kf : Z8;
      }
    }
    __syncthreads();   // sQK dead -> Pb strips may overlay it

    // waves 0-6 overlay sQK (7 x 2176 shorts = exactly 15232); wave 7 -> annex
    unsigned short* Pb = (wv8 < 7) ? (smem + wv8*16*PSTR2) : sPx;

    // ---- phase B: V projection (reads sF only) -> V^T into Pb
    {
      short8 bV[4];
      const unsigned short* wr = wqkv + (h*16 + c)*128 + q*8 + 2*128*128;
      #pragma unroll
      for (int kk = 0; kk < 4; ++kk) bV[kk] = *(const short8*)(wr + kk*32);
      const float bv_c = ipb[256 + h*16 + c];
      #pragma unroll
      for (int t = 0; t < 7; ++t) if (t < T){
        f32x4 vt = Z4;
        #pragma unroll
        for (int kk = 0; kk < 4; ++kk){
          const short8 aF = *(const short8*)&sF[(16*t + c)*STR + kk*32 + q*8];
          vt = MFMA_B16(aF, bV[kk], vt);
        }
        #pragma unroll
        for (int r = 0; r < 4; ++r){
          const int key = 16*t + 4*q + r;
          vt[r] = (key < Lv) ? (vt[r] + bv_c) : 0.f;
        }
        *(short4v*)&Pb[c*PSTR2 + 16*t + 4*q] = pack4(vt);
      }
      // zero tail cols [112,128): PV/vBf's last 32-key group covers tile 7
      // (written by neither V^T nor P) when T=7.
      const short4v z4 = {0,0,0,0};
      *(short4v*)&Pb[c*PSTR2 + 112 + 4*q] = z4;
    }

    short8 vBf[4];
    #pragma unroll
    for (int u = 0; u < 4; ++u) if (u < ((T+1)>>1))
      vBf[u] = *(const short8*)&Pb[c*PSTR2 + 32*u + q*8];

    // ---- scores / softmax / PV (per-wave, no barriers)
    short4v of[7];
    #pragma unroll
    for (int t = 0; t < 7; ++t) if (t < T){
      f32x4 St[7];
      #pragma unroll
      for (int tk = 0; tk < 7; ++tk) if (tk < T){
        St[tk] = MFMA_B16(kBf[tk], qAf[t], Z4);     // C [key][query] = S^T
        #pragma unroll
        for (int r = 0; r < 4; ++r){
          const int key = 16*tk + 4*q + r;
          if (key >= Lv) St[tk][r] = -1e30f;
        }
      }
      f32x4 mm = {-1e30f,-1e30f,-1e30f,-1e30f};
      #pragma unroll
      for (int tk = 0; tk < 7; ++tk) if (tk < T){
        mm[0]=fmaxf(mm[0],St[tk][0]); mm[1]=fmaxf(mm[1],St[tk][1]);
        mm[2]=fmaxf(mm[2],St[tk][2]); mm[3]=fmaxf(mm[3],St[tk][3]);
      }
      float m = fmaxf(fmaxf(mm[0],mm[1]), fmaxf(mm[2],mm[3]));
      m = fmaxf(m, __shfl_xor(m, 16));
      m = fmaxf(m, __shfl_xor(m, 32));
      f32x4 ss = Z4;
      #pragma unroll
      for (int tk = 0; tk < 7; ++tk) if (tk < T){
        #pragma unroll
        for (int r = 0; r < 4; ++r){
          float e = __expf(St[tk][r] - m);
          St[tk][r] = e; ss[r] += e;
        }
      }
      float sum = (ss[0]+ss[1]) + (ss[2]+ss[3]);
      sum += __shfl_xor(sum, 16);
      sum += __shfl_xor(sum, 32);
      const float inv = 1.0f / sum;
      #pragma unroll
      for (int tk = 0; tk < 7; ++tk) if (tk < T){
        short4v p4;
        #pragma unroll
        for (int r = 0; r < 4; ++r) p4[r] = (short)f2bf(St[tk][r] * inv);
        *(short4v*)&Pb[c*PSTR2 + 16*tk + 4*q] = p4;
      }
      f32x4 o = Z4;
      #pragma unroll
      for (int u = 0; u < 4; ++u) if (u < ((T+1)>>1)){
        const short8 ap = *(const short8*)&Pb[c*PSTR2 + 32*u + q*8];
        o = MFMA_B16(ap, vBf[u], o);
      }
      short4v ob;
      #pragma unroll
      for (int r = 0; r < 4; ++r) ob[r] = (short)f2bf(o[r]);
      of[t] = ob;
    }

    __syncthreads();   // all waves done with sF reads and P strips
    #pragma unroll
    for (int t = 0; t < 7; ++t) if (t < T){
      #pragma unroll
      for (int r = 0; r < 4; ++r)
        sF[(16*t + 4*q + r)*STR + h*16 + c] = (unsigned short)of[t][r];
    }
    __syncthreads();   // O complete

    // ---- out projection: wave handles tile t = wv8 (waves 0..T-1 active)
    {
      const int t = wv8;
      if (t < T){
        float bo_r[8];
        #pragma unroll
        for (int ct = 0; ct < 8; ++ct) bo_r[ct] = opb[ct*16 + c];
        f32x4 acc[8];
        #pragma unroll
        for (int ct = 0; ct < 8; ++ct) acc[ct] = Z4;
        #pragma unroll
        for (int p = 0; p < 4; ++p){
          const short8 ao = *(const short8*)&sF[(16*t + c)*STR + p*32 + q*8];
          #pragma unroll
          for (int ct = 0; ct < 8; ++ct){
            const short8 bw = *(const short8*)&wout[(ct*16 + c)*128 + p*32 + q*8];
            acc[ct] = MFMA_B16(ao, bw, acc[ct]);
          }
        }
        #pragma unroll
        for (int r = 0; r < 4; ++r){
          const int l = 16*t + 4*q + r;
          if (l < Lv){
            const int tok = inds2[ibase + l];
            float* orow = out + (long)tok*128;
            #pragma unroll
            for (int ct = 0; ct < 8; ++ct)
              orow[ct*16 + c] = acc[ct][r] + bo_r[ct];
          }
        }
      }
    }
  } else {
    // ============================ group1 path ============================
    // (R12 body verbatim; uses first 76800 B of LDS)
    const int wv8 = tid >> 6;                  // 0..7
    const int wh  = wv8 >> 2;                  // window half 0/1
    const int wv  = wv8 & 3;                   // wave within half
    const int lane = tid & 63, c = lane & 15, q = lane >> 4;

    unsigned short* base = smem + wh*HALF3;
    unsigned short* sQK = base;                     // [48][STR]
    unsigned short* sF  = base + 48*STR;            // [48][STR], O later
    unsigned short* sPb = base + 2*48*STR;          // 4 x [16][PSTR3]
    unsigned short* sTs = sPb + 4*16*PSTR3;         // 4 x [16][STRT3]

    const int w = (b - 1024)*2 + wh;
    const int LW = 36;
    const int Lv = wh ? 18 : 36;
    const int T  = wh ? 2 : 3;
    const long ibase = (long)w * LW;

    {
      const int ltid = tid & 255;
      const int rg = ltid >> 4, ch = ltid & 15;
      #pragma unroll
      for (int s = 0; s < TT3; ++s){
        if (s < T){
          const int row = s*16 + rg;
          short8 fv = Z8, qv = Z8;
          if (row < Lv){
            const int tok = inds1[ibase + row];
            const float* fr = feat + (long)tok*128 + ch*8;
            const float* pr = pos1 + (ibase + row)*128 + ch*8;
            f32x4 f0 = *(const f32x4*)fr, f1 = *(const f32x4*)(fr+4);
            f32x4 p0 = *(const f32x4*)pr, p1 = *(const f32x4*)(pr+4);
            fv = pack8(f0, f1); qv = pack8(f0+p0, f1+p1);
          }
          *(short8*)&sF [row*STR + ch*8] = fv;
          *(short8*)&sQK[row*STR + ch*8] = qv;
        }
      }
    }
    __syncthreads();

    unsigned short* Pb = sPb + wv*16*PSTR3;
    unsigned short* Ts = sTs + wv*16*STRT3;
    short4v of[2][TT3];

    #pragma unroll
    for (int hh = 0; hh < 2; ++hh){
      const int h = wv*2 + hh;
      short8 bQ[4], bK[4], bV[4];
      const unsigned short* wr = wqkv + (h*16 + c)*128 + q*8;
      #pragma unroll
      for (int kk = 0; kk < 4; ++kk){
        bQ[kk] = *(const short8*)(wr + kk*32);
        bK[kk] = *(const short8*)(wr + kk*32 + 128*128);
        bV[kk] = *(const short8*)(wr + kk*32 + 2*128*128);
      }
      float bq_r[4], bk_r[4];
      #pragma unroll
      for (int r = 0; r < 4; ++r){
        bq_r[r] = ipb[h*16 + 4*q + r];
        bk_r[r] = ipb[128 + h*16 + 4*q + r];
      }
      const float bv_c = ipb[256 + h*16 + c];

      short8 qAf[TT3], kBf[TT3];

      #pragma unroll
      for (int t = 0; t < TT3; ++t) if (t < T){
        f32x4 qt = Z4, kt = Z4, vt = Z4;
        #pragma unroll
        for (int kk = 0; kk < 4; ++kk){
          const short8 aQ = *(const short8*)&sQK[(16*t + c)*STR + kk*32 + q*8];
          const short8 aF = *(const short8*)&sF [(16*t + c)*STR + kk*32 + q*8];
          qt = MFMA_B16(bQ[kk], aQ, qt);
          kt = MFMA_B16(bK[kk], aQ, kt);
          vt = MFMA_B16(aF, bV[kk], vt);
        }
        #pragma unroll
        for (int r = 0; r < 4; ++r){
          qt[r] = (qt[r] + bq_r[r]) * 0.25f;
          kt[r] += bk_r[r];
          const int key = 16*t + 4*q + r;
          vt[r] = (key < Lv) ? (vt[r] + bv_c) : 0.f;
        }
        *(short4v*)&Pb[c*PSTR3 + 16*t + 4*q]   = pack4(vt);
        *(short4v*)&Ts[c*STRT3 + 4*q]          = pack4(qt);
        *(short4v*)&Pb[c*PSTR3 + KOFF3 + 4*q]  = pack4(kt);
        const short8 qf = *(const short8*)&Ts[c*STRT3 + q*8];
        const short8 kf = *(const short8*)&Pb[c*PSTR3 + KOFF3 + q*8];
        qAf[t] = (q < 2) ? qf : Z8;
        kBf[t] = (q < 2) ? kf : Z8;
      }
      {
        const short4v z4 = {0,0,0,0};
        *(short4v*)&Pb[c*PSTR3 + KOFF3 + 4*q] = z4;
      }

      short8 vBf[2];
      #pragma unroll
      for (int u = 0; u < 2; ++u) if (u < ((T+1)>>1))
        vBf[u] = *(const short8*)&Pb[c*PSTR3 + 32*u + q*8];

      #pragma unroll
      for (int t = 0; t < TT3; ++t) if (t < T){
        f32x4 St[TT3];
        #pragma unroll
        for (int tk = 0; tk < TT3; ++tk) if (tk < T){
          St[tk] = MFMA_B16(kBf[tk], qAf[t], Z4);     // C [key][query] = S^T
          #pragma unroll
          for (int r = 0; r < 4; ++r){
            const int key = 16*tk + 4*q + r;
            if (key >= Lv) St[tk][r] = -1e30f;
          }
        }
        f32x4 mm = {-1e30f,-1e30f,-1e30f,-1e30f};
        #pragma unroll
        for (int tk = 0; tk < TT3; ++tk) if (tk < T){
          mm[0]=fmaxf(mm[0],St[tk][0]); mm[1]=fmaxf(mm[1],St[tk][1]);
          mm[2]=fmaxf(mm[2],St[tk][2]); mm[3]=fmaxf(mm[3],St[tk][3]);
        }
        float m = fmaxf(fmaxf(mm[0],mm[1]), fmaxf(mm[2],mm[3]));
        m = fmaxf(m, __shfl_xor(m, 16));
        m = fmaxf(m, __shfl_xor(m, 32));
        f32x4 ss = Z4;
        #pragma unroll
        for (int tk = 0; tk < TT3; ++tk) if (tk < T){
          #pragma unroll
          for (int r = 0; r < 4; ++r){
            float e = __expf(St[tk][r] - m);
            St[tk][r] = e; ss[r] += e;
          }
        }
        float sum = (ss[0]+ss[1]) + (ss[2]+ss[3]);
        sum += __shfl_xor(sum, 16);
        sum += __shfl_xor(sum, 32);
        const float inv = 1.0f / sum;
        #pragma unroll
        for (int tk = 0; tk < TT3; ++tk) if (tk < T){
          short4v p4;
          #pragma unroll
          for (int r = 0; r < 4; ++r) p4[r] = (short)f2bf(St[tk][r] * inv);
          *(short4v*)&Pb[c*PSTR3 + 16*tk + 4*q] = p4;
        }
        f32x4 o = Z4;
        #pragma unroll
        for (int u = 0; u < 2; ++u) if (u < ((T+1)>>1)){
          const short8 ap = *(const short8*)&Pb[c*PSTR3 + 32*u + q*8];
          o = MFMA_B16(ap, vBf[u], o);
        }
        short4v ob;
        #pragma unroll
        for (int r = 0; r < 4; ++r) ob[r] = (short)f2bf(o[r]);
        of[hh][t] = ob;
      }
    } // hh

    __syncthreads();   // all waves done reading sQK/sF (both halves)
    #pragma unroll
    for (int hh = 0; hh < 2; ++hh){
      const int h = wv*2 + hh;
      #pragma unroll
      for (int t = 0; t < TT3; ++t) if (t < T){
        #pragma unroll
        for (int r = 0; r < 4; ++r)
          sF[(16*t + 4*q + r)*STR + h*16 + c] = (unsigned short)of[hh][t][r];
      }
    }
    __syncthreads();   // O complete

    // ---- out projection: wave handles query tile wv of its window
    {
      const int t = wv;
      if (t < T){
        float bo_r[8];
        #pragma unroll
        for (int ct = 0; ct < 8; ++ct) bo_r[ct] = opb[ct*16 + c];
        f32x4 acc[8];
        #pragma unroll
        for (int ct = 0; ct < 8; ++ct) acc[ct] = Z4;
        #pragma unroll
        for (int p = 0; p < 4; ++p){
          const short8 ao = *(const short8*)&sF[(16*t + c)*STR + p*32 + q*8];
          #pragma unroll
          for (int ct = 0; ct < 8; ++ct){
            const short8 bw = *(const short8*)&wout[(ct*16 + c)*128 + p*32 + q*8];
            acc[ct] = MFMA_B16(ao, bw, acc[ct]);
          }
        }
        #pragma unroll
        for (int r = 0; r < 4; ++r){
          const int l = 16*t + 4*q + r;
          if (l < Lv){
            const int tok = inds1[ibase + l];
            float* orow = out + (long)tok*128;
            #pragma unroll
            for (int ct = 0; ct < 8; ++ct)
              orow[ct*16 + c] = acc[ct][r] + bo_r[ct];
          }
        }
      }
    }
  }
}

extern "C" void kernel_launch(void* const* d_in, const int* in_sizes, int n_in,
                              void* d_out, int out_size, void* d_ws, size_t ws_size,
                              hipStream_t stream) {
  const float* feat = (const float*)d_in[0];
  const float* pos1 = (const float*)d_in[1];
  const float* pos2 = (const float*)d_in[2];
  const float* ipw  = (const float*)d_in[3];
  const float* ipb  = (const float*)d_in[4];
  const float* opw  = (const float*)d_in[5];
  const float* opb  = (const float*)d_in[6];
  const int*   inds1 = (const int*)d_in[7];
  const int*   inds2 = (const int*)d_in[8];
  float* out = (float*)d_out;
  unsigned short* wbf = (unsigned short*)d_ws;   // 384*128 + 128*128 bf16
  unsigned short* wob = wbf + 384*128;

  prep_w<<<dim3(256), dim3(256), 0, stream>>>(ipw, opw, wbf);

  // merged: LDS request = g1 layout = 2*HALF3*2 = 76800 B -> 2 blocks/CU.
  // g2 path uses 2*112*STR*2 + 8*16*STRT2*2 + 16*PSTR2*2 = 71424 B of it.
  const int lds = 2*HALF3*2;
  hipFuncSetAttribute((const void*)fused_all,
                      hipFuncAttributeMaxDynamicSharedMemorySize, lds);
  fused_all<<<dim3(1024 + 2048), dim3(512), lds, stream>>>(
      feat, pos1, pos2, inds1, inds2, wbf, wob, ipb, opb, out);
}

// Round 14
// 404.896 us; speedup vs baseline: 1.3242x; 1.0002x over previous
//
#include <hip/hip_runtime.h>

typedef __attribute__((ext_vector_type(4))) float f32x4;
typedef __attribute__((ext_vector_type(8))) short short8;
typedef __attribute__((ext_vector_type(4))) short short4v;

#define MFMA_B16(a,b,c) __builtin_amdgcn_mfma_f32_16x16x32_bf16((a),(b),(c),0,0,0)

static __device__ __forceinline__ unsigned short f2bf(float x){
  unsigned int u = __float_as_uint(x);
  u += 0x7fffu + ((u >> 16) & 1u);
  return (unsigned short)(u >> 16);
}

static __device__ __forceinline__ short8 pack8(f32x4 a, f32x4 b){
  short8 r;
  r[0]=(short)f2bf(a[0]); r[1]=(short)f2bf(a[1]); r[2]=(short)f2bf(a[2]); r[3]=(short)f2bf(a[3]);
  r[4]=(short)f2bf(b[0]); r[5]=(short)f2bf(b[1]); r[6]=(short)f2bf(b[2]); r[7]=(short)f2bf(b[3]);
  return r;
}

static __device__ __forceinline__ short4v pack4(const f32x4& a){
  short4v r;
  r[0]=(short)f2bf(a[0]); r[1]=(short)f2bf(a[1]); r[2]=(short)f2bf(a[2]); r[3]=(short)f2bf(a[3]);
  return r;
}

__global__ void prep_w(const float* __restrict__ ipw, const float* __restrict__ opw,
                       unsigned short* __restrict__ wbf){
  int i = blockIdx.x * 256 + threadIdx.x;
  float v = (i < 384*128) ? ipw[i] : opw[i - 384*128];
  wbf[i] = f2bf(v);
}

#define STR 136    // shorts per staged row (128 + 8 pad)

// group2 geometry (TTP=7), 1 head per wave
#define PSTR2 (16*8 + 8)   // 136
#define STRT2 24

// group1 geometry (TT3=3)
#define TT3 3
#define PSTR3 (16*(TT3+1) + 8)   // 72
#define STRT3 24
#define KOFF3 (16*TT3)           // 48
#define HALF3 (2*48*STR + 4*16*PSTR3 + 4*16*STRT3)   // shorts per window half

// =============================== merged kernel ===============================
// R13 body verbatim.  Occupancy attribute changed: amdgpu_waves_per_eu(4,4)
// pins the register budget to exactly 128 VGPR (4 waves/EU) — LDS caps us at
// 2 blocks/CU = 4 waves/EU anyway, so R13's compiler choice of 64 VGPR
// (aiming at an unreachable 8/EU bucket) only bought spills and lost ILP.
__global__ __attribute__((amdgpu_flat_work_group_size(512, 512),
                          amdgpu_waves_per_eu(4, 4)))
void fused_all(const float* __restrict__ feat,
               const float* __restrict__ pos1, const float* __restrict__ pos2,
               const int* __restrict__ inds1, const int* __restrict__ inds2,
               const unsigned short* __restrict__ wqkv,
               const unsigned short* __restrict__ wout,
               const float* __restrict__ ipb, const float* __restrict__ opb,
               float* __restrict__ out)
{
  extern __shared__ __align__(16) unsigned short smem[];
  const int b  = blockIdx.x;
  const int tid = threadIdx.x;
  const short8 Z8 = {0,0,0,0,0,0,0,0};
  const f32x4  Z4 = {0.f,0.f,0.f,0.f};

  if (b < 1024){
    // ============================ group2 path ============================
    unsigned short* sQK = smem;                     // [112][STR]; Pb overlay later
    unsigned short* sF  = smem + 112*STR;           // [112][STR]; O buffer later
    unsigned short* sTs = smem + 2*112*STR;         // 8 x [16][STRT2]
    unsigned short* sPx = sTs + 8*16*STRT2;         // wave 7's Pb annex [16][PSTR2]

    const int w  = b;
    const int Lv = (w & 1) ? 50 : 100;
    const int T  = (Lv + 15) >> 4;                  // 7 or 4
    const long ibase = (long)w * 100;
    const int wv8 = tid >> 6, lane = tid & 63, c = lane & 15, q = lane >> 4;

    // ---- staging: all 512 threads, 32 rows x 16 chunks per sweep (4 sweeps)
    {
      const int rg = tid >> 4, ch = tid & 15;       // rg 0..31
      #pragma unroll
      for (int s = 0; s < 4; ++s){
        const int row = s*32 + rg;
        if (row < 16*T){
          short8 fv = Z8, qv = Z8;
          if (row < Lv){
            const int tok = inds2[ibase + row];
            const float* fr = feat + (long)tok*128 + ch*8;
            const float* pr = pos2 + (ibase + row)*128 + ch*8;
            f32x4 f0 = *(const f32x4*)fr, f1 = *(const f32x4*)(fr+4);
            f32x4 p0 = *(const f32x4*)pr, p1 = *(const f32x4*)(pr+4);
            fv = pack8(f0, f1); qv = pack8(f0+p0, f1+p1);
          }
          *(short8*)&sF [row*STR + ch*8] = fv;
          *(short8*)&sQK[row*STR + ch*8] = qv;
        }
      }
    }
    __syncthreads();

    const int h = wv8;                              // one head per wave
    unsigned short* Ts = sTs + wv8*16*STRT2;
    short8 qAf[7], kBf[7];

    // ---- phase A: Q,K projection (reads sQK)
    {
      short8 bQ[4], bK[4];
      const unsigned short* wr = wqkv + (h*16 + c)*128 + q*8;
      #pragma unroll
      for (int kk = 0; kk < 4; ++kk){
        bQ[kk] = *(const short8*)(wr + kk*32);
        bK[kk] = *(const short8*)(wr + kk*32 + 128*128);
      }
      float bq_r[4], bk_r[4];
      #pragma unroll
      for (int r = 0; r < 4; ++r){
        bq_r[r] = ipb[h*16 + 4*q + r];
        bk_r[r] = ipb[128 + h*16 + 4*q + r];
      }
      #pragma unroll
      for (int t = 0; t < 7; ++t) if (t < T){
        f32x4 qt = Z4, kt = Z4;
        #pragma unroll
        for (int kk = 0; kk < 4; ++kk){
          const short8 aQ = *(const short8*)&sQK[(16*t + c)*STR + kk*32 + q*8];
          qt = MFMA_B16(bQ[kk], aQ, qt);
          kt = MFMA_B16(bK[kk], aQ, kt);
        }
        #pragma unroll
        for (int r = 0; r < 4; ++r){
          qt[r] = (qt[r] + bq_r[r]) * 0.25f;
          kt[r] += bk_r[r];
        }
        *(short4v*)&Ts[c*STRT2 + 4*q] = pack4(qt);
        const short8 qf = *(const short8*)&Ts[c*STRT2 + q*8];
        qAf[t] = (q < 2) ? qf : Z8;
        *(short4v*)&Ts[c*STRT2 + 4*q] = pack4(kt);
        const short8 kf = *(const short8*)&Ts[c*STRT2 + q*8];
        kBf[t] = (q < 2) ? kf : Z8;
      }
    }
    __syncthreads();   // sQK dead -> Pb strips may overlay it

    // waves 0-6 overlay sQK (7 x 2176 shorts = exactly 15232); wave 7 -> annex
    unsigned short* Pb = (wv8 < 7) ? (smem + wv8*16*PSTR2) : sPx;

    // ---- phase B: V projection (reads sF only) -> V^T into Pb
    {
      short8 bV[4];
      const unsigned short* wr = wqkv + (h*16 + c)*128 + q*8 + 2*128*128;
      #pragma unroll
      for (int kk = 0; kk < 4; ++kk) bV[kk] = *(const short8*)(wr + kk*32);
      const float bv_c = ipb[256 + h*16 + c];
      #pragma unroll
      for (int t = 0; t < 7; ++t) if (t < T){
        f32x4 vt = Z4;
        #pragma unroll
        for (int kk = 0; kk < 4; ++kk){
          const short8 aF = *(const short8*)&sF[(16*t + c)*STR + kk*32 + q*8];
          vt = MFMA_B16(aF, bV[kk], vt);
        }
        #pragma unroll
        for (int r = 0; r < 4; ++r){
          const int key = 16*t + 4*q + r;
          vt[r] = (key < Lv) ? (vt[r] + bv_c) : 0.f;
        }
        *(short4v*)&Pb[c*PSTR2 + 16*t + 4*q] = pack4(vt);
      }
      // zero tail cols [112,128): PV/vBf's last 32-key group covers tile 7
      // (written by neither V^T nor P) when T=7.
      const short4v z4 = {0,0,0,0};
      *(short4v*)&Pb[c*PSTR2 + 112 + 4*q] = z4;
    }

    short8 vBf[4];
    #pragma unroll
    for (int u = 0; u < 4; ++u) if (u < ((T+1)>>1))
      vBf[u] = *(const short8*)&Pb[c*PSTR2 + 32*u + q*8];

    // ---- scores / softmax / PV (per-wave, no barriers)
    short4v of[7];
    #pragma unroll
    for (int t = 0; t < 7; ++t) if (t < T){
      f32x4 St[7];
      #pragma unroll
      for (int tk = 0; tk < 7; ++tk) if (tk < T){
        St[tk] = MFMA_B16(kBf[tk], qAf[t], Z4);     // C [key][query] = S^T
        #pragma unroll
        for (int r = 0; r < 4; ++r){
          const int key = 16*tk + 4*q + r;
          if (key >= Lv) St[tk][r] = -1e30f;
        }
      }
      f32x4 mm = {-1e30f,-1e30f,-1e30f,-1e30f};
      #pragma unroll
      for (int tk = 0; tk < 7; ++tk) if (tk < T){
        mm[0]=fmaxf(mm[0],St[tk][0]); mm[1]=fmaxf(mm[1],St[tk][1]);
        mm[2]=fmaxf(mm[2],St[tk][2]); mm[3]=fmaxf(mm[3],St[tk][3]);
      }
      float m = fmaxf(fmaxf(mm[0],mm[1]), fmaxf(mm[2],mm[3]));
      m = fmaxf(m, __shfl_xor(m, 16));
      m = fmaxf(m, __shfl_xor(m, 32));
      f32x4 ss = Z4;
      #pragma unroll
      for (int tk = 0; tk < 7; ++tk) if (tk < T){
        #pragma unroll
        for (int r = 0; r < 4; ++r){
          float e = __expf(St[tk][r] - m);
          St[tk][r] = e; ss[r] += e;
        }
      }
      float sum = (ss[0]+ss[1]) + (ss[2]+ss[3]);
      sum += __shfl_xor(sum, 16);
      sum += __shfl_xor(sum, 32);
      const float inv = 1.0f / sum;
      #pragma unroll
      for (int tk = 0; tk < 7; ++tk) if (tk < T){
        short4v p4;
        #pragma unroll
        for (int r = 0; r < 4; ++r) p4[r] = (short)f2bf(St[tk][r] * inv);
        *(short4v*)&Pb[c*PSTR2 + 16*tk + 4*q] = p4;
      }
      f32x4 o = Z4;
      #pragma unroll
      for (int u = 0; u < 4; ++u) if (u < ((T+1)>>1)){
        const short8 ap = *(const short8*)&Pb[c*PSTR2 + 32*u + q*8];
        o = MFMA_B16(ap, vBf[u], o);
      }
      short4v ob;
      #pragma unroll
      for (int r = 0; r < 4; ++r) ob[r] = (short)f2bf(o[r]);
      of[t] = ob;
    }

    __syncthreads();   // all waves done with sF reads and P strips
    #pragma unroll
    for (int t = 0; t < 7; ++t) if (t < T){
      #pragma unroll
      for (int r = 0; r < 4; ++r)
        sF[(16*t + 4*q + r)*STR + h*16 + c] = (unsigned short)of[t][r];
    }
    __syncthreads();   // O complete

    // ---- out projection: wave handles tile t = wv8 (waves 0..T-1 active)
    {
      const int t = wv8;
      if (t < T){
        float bo_r[8];
        #pragma unroll
        for (int ct = 0; ct < 8; ++ct) bo_r[ct] = opb[ct*16 + c];
        f32x4 acc[8];
        #pragma unroll
        for (int ct = 0; ct < 8; ++ct) acc[ct] = Z4;
        #pragma unroll
        for (int p = 0; p < 4; ++p){
          const short8 ao = *(const short8*)&sF[(16*t + c)*STR + p*32 + q*8];
          #pragma unroll
          for (int ct = 0; ct < 8; ++ct){
            const short8 bw = *(const short8*)&wout[(ct*16 + c)*128 + p*32 + q*8];
            acc[ct] = MFMA_B16(ao, bw, acc[ct]);
          }
        }
        #pragma unroll
        for (int r = 0; r < 4; ++r){
          const int l = 16*t + 4*q + r;
          if (l < Lv){
            const int tok = inds2[ibase + l];
            float* orow = out + (long)tok*128;
            #pragma unroll
            for (int ct = 0; ct < 8; ++ct)
              orow[ct*16 + c] = acc[ct][r] + bo_r[ct];
          }
        }
      }
    }
  } else {
    // ============================ group1 path ============================
    // (R12 body verbatim; uses first 76800 B of LDS)
    const int wv8 = tid >> 6;                  // 0..7
    const int wh  = wv8 >> 2;                  // window half 0/1
    const int wv  = wv8 & 3;                   // wave within half
    const int lane = tid & 63, c = lane & 15, q = lane >> 4;

    unsigned short* base = smem + wh*HALF3;
    unsigned short* sQK = base;                     // [48][STR]
    unsigned short* sF  = base + 48*STR;            // [48][STR], O later
    unsigned short* sPb = base + 2*48*STR;          // 4 x [16][PSTR3]
    unsigned short* sTs = sPb + 4*16*PSTR3;         // 4 x [16][STRT3]

    const int w = (b - 1024)*2 + wh;
    const int LW = 36;
    const int Lv = wh ? 18 : 36;
    const int T  = wh ? 2 : 3;
    const long ibase = (long)w * LW;

    {
      const int ltid = tid & 255;
      const int rg = ltid >> 4, ch = ltid & 15;
      #pragma unroll
      for (int s = 0; s < TT3; ++s){
        if (s < T){
          const int row = s*16 + rg;
          short8 fv = Z8, qv = Z8;
          if (row < Lv){
            const int tok = inds1[ibase + row];
            const float* fr = feat + (long)tok*128 + ch*8;
            const float* pr = pos1 + (ibase + row)*128 + ch*8;
            f32x4 f0 = *(const f32x4*)fr, f1 = *(const f32x4*)(fr+4);
            f32x4 p0 = *(const f32x4*)pr, p1 = *(const f32x4*)(pr+4);
            fv = pack8(f0, f1); qv = pack8(f0+p0, f1+p1);
          }
          *(short8*)&sF [row*STR + ch*8] = fv;
          *(short8*)&sQK[row*STR + ch*8] = qv;
        }
      }
    }
    __syncthreads();

    unsigned short* Pb = sPb + wv*16*PSTR3;
    unsigned short* Ts = sTs + wv*16*STRT3;
    short4v of[2][TT3];

    #pragma unroll
    for (int hh = 0; hh < 2; ++hh){
      const int h = wv*2 + hh;
      short8 bQ[4], bK[4], bV[4];
      const unsigned short* wr = wqkv + (h*16 + c)*128 + q*8;
      #pragma unroll
      for (int kk = 0; kk < 4; ++kk){
        bQ[kk] = *(const short8*)(wr + kk*32);
        bK[kk] = *(const short8*)(wr + kk*32 + 128*128);
        bV[kk] = *(const short8*)(wr + kk*32 + 2*128*128);
      }
      float bq_r[4], bk_r[4];
      #pragma unroll
      for (int r = 0; r < 4; ++r){
        bq_r[r] = ipb[h*16 + 4*q + r];
        bk_r[r] = ipb[128 + h*16 + 4*q + r];
      }
      const float bv_c = ipb[256 + h*16 + c];

      short8 qAf[TT3], kBf[TT3];

      #pragma unroll
      for (int t = 0; t < TT3; ++t) if (t < T){
        f32x4 qt = Z4, kt = Z4, vt = Z4;
        #pragma unroll
        for (int kk = 0; kk < 4; ++kk){
          const short8 aQ = *(const short8*)&sQK[(16*t + c)*STR + kk*32 + q*8];
          const short8 aF = *(const short8*)&sF [(16*t + c)*STR + kk*32 + q*8];
          qt = MFMA_B16(bQ[kk], aQ, qt);
          kt = MFMA_B16(bK[kk], aQ, kt);
          vt = MFMA_B16(aF, bV[kk], vt);
        }
        #pragma unroll
        for (int r = 0; r < 4; ++r){
          qt[r] = (qt[r] + bq_r[r]) * 0.25f;
          kt[r] += bk_r[r];
          const int key = 16*t + 4*q + r;
          vt[r] = (key < Lv) ? (vt[r] + bv_c) : 0.f;
        }
        *(short4v*)&Pb[c*PSTR3 + 16*t + 4*q]   = pack4(vt);
        *(short4v*)&Ts[c*STRT3 + 4*q]          = pack4(qt);
        *(short4v*)&Pb[c*PSTR3 + KOFF3 + 4*q]  = pack4(kt);
        const short8 qf = *(const short8*)&Ts[c*STRT3 + q*8];
        const short8 kf = *(const short8*)&Pb[c*PSTR3 + KOFF3 + q*8];
        qAf[t] = (q < 2) ? qf : Z8;
        kBf[t] = (q < 2) ? kf : Z8;
      }
      {
        const short4v z4 = {0,0,0,0};
        *(short4v*)&Pb[c*PSTR3 + KOFF3 + 4*q] = z4;
      }

      short8 vBf[2];
      #pragma unroll
      for (int u = 0; u < 2; ++u) if (u < ((T+1)>>1))
        vBf[u] = *(const short8*)&Pb[c*PSTR3 + 32*u + q*8];

      #pragma unroll
      for (int t = 0; t < TT3; ++t) if (t < T){
        f32x4 St[TT3];
        #pragma unroll
        for (int tk = 0; tk < TT3; ++tk) if (tk < T){
          St[tk] = MFMA_B16(kBf[tk], qAf[t], Z4);     // C [key][query] = S^T
          #pragma unroll
          for (int r = 0; r < 4; ++r){
            const int key = 16*tk + 4*q + r;
            if (key >= Lv) St[tk][r] = -1e30f;
          }
        }
        f32x4 mm = {-1e30f,-1e30f,-1e30f,-1e30f};
        #pragma unroll
        for (int tk = 0; tk < TT3; ++tk) if (tk < T){
          mm[0]=fmaxf(mm[0],St[tk][0]); mm[1]=fmaxf(mm[1],St[tk][1]);
          mm[2]=fmaxf(mm[2],St[tk][2]); mm[3]=fmaxf(mm[3],St[tk][3]);
        }
        float m = fmaxf(fmaxf(mm[0],mm[1]), fmaxf(mm[2],mm[3]));
        m = fmaxf(m, __shfl_xor(m, 16));
        m = fmaxf(m, __shfl_xor(m, 32));
        f32x4 ss = Z4;
        #pragma unroll
        for (int tk = 0; tk < TT3; ++tk) if (tk < T){
          #pragma unroll
          for (int r = 0; r < 4; ++r){
            float e = __expf(St[tk][r] - m);
            St[tk][r] = e; ss[r] += e;
          }
        }
        float sum = (ss[0]+ss[1]) + (ss[2]+ss[3]);
        sum += __shfl_xor(sum, 16);
        sum += __shfl_xor(sum, 32);
        const float inv = 1.0f / sum;
        #pragma unroll
        for (int tk = 0; tk < TT3; ++tk) if (tk < T){
          short4v p4;
          #pragma unroll
          for (int r = 0; r < 4; ++r) p4[r] = (short)f2bf(St[tk][r] * inv);
          *(short4v*)&Pb[c*PSTR3 + 16*tk + 4*q] = p4;
        }
        f32x4 o = Z4;
        #pragma unroll
        for (int u = 0; u < 2; ++u) if (u < ((T+1)>>1)){
          const short8 ap = *(const short8*)&Pb[c*PSTR3 + 32*u + q*8];
          o = MFMA_B16(ap, vBf[u], o);
        }
        short4v ob;
        #pragma unroll
        for (int r = 0; r < 4; ++r) ob[r] = (short)f2bf(o[r]);
        of[hh][t] = ob;
      }
    } // hh

    __syncthreads();   // all waves done reading sQK/sF (both halves)
    #pragma unroll
    for (int hh = 0; hh < 2; ++hh){
      const int h = wv*2 + hh;
      #pragma unroll
      for (int t = 0; t < TT3; ++t) if (t < T){
        #pragma unroll
        for (int r = 0; r < 4; ++r)
          sF[(16*t + 4*q + r)*STR + h*16 + c] = (unsigned short)of[hh][t][r];
      }
    }
    __syncthreads();   // O complete

    // ---- out projection: wave handles query tile wv of its window
    {
      const int t = wv;
      if (t < T){
        float bo_r[8];
        #pragma unroll
        for (int ct = 0; ct < 8; ++ct) bo_r[ct] = opb[ct*16 + c];
        f32x4 acc[8];
        #pragma unroll
        for (int ct = 0; ct < 8; ++ct) acc[ct] = Z4;
        #pragma unroll
        for (int p = 0; p < 4; ++p){
          const short8 ao = *(const short8*)&sF[(16*t + c)*STR + p*32 + q*8];
          #pragma unroll
          for (int ct = 0; ct < 8; ++ct){
            const short8 bw = *(const short8*)&wout[(ct*16 + c)*128 + p*32 + q*8];
            acc[ct] = MFMA_B16(ao, bw, acc[ct]);
          }
        }
        #pragma unroll
        for (int r = 0; r < 4; ++r){
          const int l = 16*t + 4*q + r;
          if (l < Lv){
            const int tok = inds1[ibase + l];
            float* orow = out + (long)tok*128;
            #pragma unroll
            for (int ct = 0; ct < 8; ++ct)
              orow[ct*16 + c] = acc[ct][r] + bo_r[ct];
          }
        }
      }
    }
  }
}

extern "C" void kernel_launch(void* const* d_in, const int* in_sizes, int n_in,
                              void* d_out, int out_size, void* d_ws, size_t ws_size,
                              hipStream_t stream) {
  const float* feat = (const float*)d_in[0];
  const float* pos1 = (const float*)d_in[1];
  const float* pos2 = (const float*)d_in[2];
  const float* ipw  = (const float*)d_in[3];
  const float* ipb  = (const float*)d_in[4];
  const float* opw  = (const float*)d_in[5];
  const float* opb  = (const float*)d_in[6];
  const int*   inds1 = (const int*)d_in[7];
  const int*   inds2 = (const int*)d_in[8];
  float* out = (float*)d_out;
  unsigned short* wbf = (unsigned short*)d_ws;   // 384*128 + 128*128 bf16
  unsigned short* wob = wbf + 384*128;

  prep_w<<<dim3(256), dim3(256), 0, stream>>>(ipw, opw, wbf);

  // merged: LDS request = g1 layout = 2*HALF3*2 = 76800 B -> 2 blocks/CU.
  // g2 path uses 2*112*STR*2 + 8*16*STRT2*2 + 16*PSTR2*2 = 71424 B of it.
  const int lds = 2*HALF3*2;
  hipFuncSetAttribute((const void*)fused_all,
                      hipFuncAttributeMaxDynamicSharedMemorySize, lds);
  fused_all<<<dim3(1024 + 2048), dim3(512), lds, stream>>>(
      feat, pos1, pos2, inds1, inds2, wbf, wob, ipb, opb, out);
}

// Round 15
// 396.422 us; speedup vs baseline: 1.3525x; 1.0214x over previous
//
#include <hip/hip_runtime.h>
#include <hip/hip_bf16.h>

typedef __attribute__((ext_vector_type(4))) float f32x4;
typedef __attribute__((ext_vector_type(8))) short short8;
typedef __attribute__((ext_vector_type(4))) short short4v;

#define MFMA_B16(a,b,c) __builtin_amdgcn_mfma_f32_16x16x32_bf16((a),(b),(c),0,0,0)

// f32 -> bf16 (RNE) via the official intrinsic: the compiler pairs adjacent
// casts into v_cvt_pk_bf16_f32 (1 op / 2 elems vs ~3 ops/elem manual).
// R9's hand-written cvt_pk asm produced NaN; the intrinsic path is the
// supported route and rounds identically to the old manual f2bf.
static __device__ __forceinline__ unsigned short f2bf(float x){
  __hip_bfloat16 b = __float2bfloat16(x);
  return __builtin_bit_cast(unsigned short, b);
}

static __device__ __forceinline__ short8 pack8(f32x4 a, f32x4 b){
  short8 r;
  r[0]=(short)f2bf(a[0]); r[1]=(short)f2bf(a[1]); r[2]=(short)f2bf(a[2]); r[3]=(short)f2bf(a[3]);
  r[4]=(short)f2bf(b[0]); r[5]=(short)f2bf(b[1]); r[6]=(short)f2bf(b[2]); r[7]=(short)f2bf(b[3]);
  return r;
}

static __device__ __forceinline__ short4v pack4(const f32x4& a){
  short4v r;
  r[0]=(short)f2bf(a[0]); r[1]=(short)f2bf(a[1]); r[2]=(short)f2bf(a[2]); r[3]=(short)f2bf(a[3]);
  return r;
}

__global__ void prep_w(const float* __restrict__ ipw, const float* __restrict__ opw,
                       unsigned short* __restrict__ wbf){
  int i = blockIdx.x * 256 + threadIdx.x;
  float v = (i < 384*128) ? ipw[i] : opw[i - 384*128];
  wbf[i] = f2bf(v);
}

#define STR 136    // shorts per staged row (128 + 8 pad)

// group2 geometry (TTP=7), 1 head per wave
#define PSTR2 (16*8 + 8)   // 136
#define STRT2 24

// group1 geometry (TT3=3)
#define TT3 3
#define PSTR3 (16*(TT3+1) + 8)   // 72
#define STRT3 24
#define KOFF3 (16*TT3)           // 48
#define HALF3 (2*48*STR + 4*16*PSTR3 + 4*16*STRT3)   // shorts per window half

// =============================== merged kernel ===============================
// R14 body verbatim; only the bf16 pack path changed (intrinsic cvt).
__global__ __attribute__((amdgpu_flat_work_group_size(512, 512),
                          amdgpu_waves_per_eu(4, 4)))
void fused_all(const float* __restrict__ feat,
               const float* __restrict__ pos1, const float* __restrict__ pos2,
               const int* __restrict__ inds1, const int* __restrict__ inds2,
               const unsigned short* __restrict__ wqkv,
               const unsigned short* __restrict__ wout,
               const float* __restrict__ ipb, const float* __restrict__ opb,
               float* __restrict__ out)
{
  extern __shared__ __align__(16) unsigned short smem[];
  const int b  = blockIdx.x;
  const int tid = threadIdx.x;
  const short8 Z8 = {0,0,0,0,0,0,0,0};
  const f32x4  Z4 = {0.f,0.f,0.f,0.f};

  if (b < 1024){
    // ============================ group2 path ============================
    unsigned short* sQK = smem;                     // [112][STR]; Pb overlay later
    unsigned short* sF  = smem + 112*STR;           // [112][STR]; O buffer later
    unsigned short* sTs = smem + 2*112*STR;         // 8 x [16][STRT2]
    unsigned short* sPx = sTs + 8*16*STRT2;         // wave 7's Pb annex [16][PSTR2]

    const int w  = b;
    const int Lv = (w & 1) ? 50 : 100;
    const int T  = (Lv + 15) >> 4;                  // 7 or 4
    const long ibase = (long)w * 100;
    const int wv8 = tid >> 6, lane = tid & 63, c = lane & 15, q = lane >> 4;

    // ---- staging: all 512 threads, 32 rows x 16 chunks per sweep (4 sweeps)
    {
      const int rg = tid >> 4, ch = tid & 15;       // rg 0..31
      #pragma unroll
      for (int s = 0; s < 4; ++s){
        const int row = s*32 + rg;
        if (row < 16*T){
          short8 fv = Z8, qv = Z8;
          if (row < Lv){
            const int tok = inds2[ibase + row];
            const float* fr = feat + (long)tok*128 + ch*8;
            const float* pr = pos2 + (ibase + row)*128 + ch*8;
            f32x4 f0 = *(const f32x4*)fr, f1 = *(const f32x4*)(fr+4);
            f32x4 p0 = *(const f32x4*)pr, p1 = *(const f32x4*)(pr+4);
            fv = pack8(f0, f1); qv = pack8(f0+p0, f1+p1);
          }
          *(short8*)&sF [row*STR + ch*8] = fv;
          *(short8*)&sQK[row*STR + ch*8] = qv;
        }
      }
    }
    __syncthreads();

    const int h = wv8;                              // one head per wave
    unsigned short* Ts = sTs + wv8*16*STRT2;
    short8 qAf[7], kBf[7];

    // ---- phase A: Q,K projection (reads sQK)
    {
      short8 bQ[4], bK[4];
      const unsigned short* wr = wqkv + (h*16 + c)*128 + q*8;
      #pragma unroll
      for (int kk = 0; kk < 4; ++kk){
        bQ[kk] = *(const short8*)(wr + kk*32);
        bK[kk] = *(const short8*)(wr + kk*32 + 128*128);
      }
      float bq_r[4], bk_r[4];
      #pragma unroll
      for (int r = 0; r < 4; ++r){
        bq_r[r] = ipb[h*16 + 4*q + r];
        bk_r[r] = ipb[128 + h*16 + 4*q + r];
      }
      #pragma unroll
      for (int t = 0; t < 7; ++t) if (t < T){
        f32x4 qt = Z4, kt = Z4;
        #pragma unroll
        for (int kk = 0; kk < 4; ++kk){
          const short8 aQ = *(const short8*)&sQK[(16*t + c)*STR + kk*32 + q*8];
          qt = MFMA_B16(bQ[kk], aQ, qt);
          kt = MFMA_B16(bK[kk], aQ, kt);
        }
        #pragma unroll
        for (int r = 0; r < 4; ++r){
          qt[r] = (qt[r] + bq_r[r]) * 0.25f;
          kt[r] += bk_r[r];
        }
        *(short4v*)&Ts[c*STRT2 + 4*q] = pack4(qt);
        const short8 qf = *(const short8*)&Ts[c*STRT2 + q*8];
        qAf[t] = (q < 2) ? qf : Z8;
        *(short4v*)&Ts[c*STRT2 + 4*q] = pack4(kt);
        const short8 kf = *(const short8*)&Ts[c*STRT2 + q*8];
        kBf[t] = (q < 2) ? kf : Z8;
      }
    }
    __syncthreads();   // sQK dead -> Pb strips may overlay it

    // waves 0-6 overlay sQK (7 x 2176 shorts = exactly 15232); wave 7 -> annex
    unsigned short* Pb = (wv8 < 7) ? (smem + wv8*16*PSTR2) : sPx;

    // ---- phase B: V projection (reads sF only) -> V^T into Pb
    {
      short8 bV[4];
      const unsigned short* wr = wqkv + (h*16 + c)*128 + q*8 + 2*128*128;
      #pragma unroll
      for (int kk = 0; kk < 4; ++kk) bV[kk] = *(const short8*)(wr + kk*32);
      const float bv_c = ipb[256 + h*16 + c];
      #pragma unroll
      for (int t = 0; t < 7; ++t) if (t < T){
        f32x4 vt = Z4;
        #pragma unroll
        for (int kk = 0; kk < 4; ++kk){
          const short8 aF = *(const short8*)&sF[(16*t + c)*STR + kk*32 + q*8];
          vt = MFMA_B16(aF, bV[kk], vt);
        }
        #pragma unroll
        for (int r = 0; r < 4; ++r){
          const int key = 16*t + 4*q + r;
          vt[r] = (key < Lv) ? (vt[r] + bv_c) : 0.f;
        }
        *(short4v*)&Pb[c*PSTR2 + 16*t + 4*q] = pack4(vt);
      }
      // zero tail cols [112,128): PV/vBf's last 32-key group covers tile 7
      // (written by neither V^T nor P) when T=7.
      const short4v z4 = {0,0,0,0};
      *(short4v*)&Pb[c*PSTR2 + 112 + 4*q] = z4;
    }

    short8 vBf[4];
    #pragma unroll
    for (int u = 0; u < 4; ++u) if (u < ((T+1)>>1))
      vBf[u] = *(const short8*)&Pb[c*PSTR2 + 32*u + q*8];

    // ---- scores / softmax / PV (per-wave, no barriers)
    short4v of[7];
    #pragma unroll
    for (int t = 0; t < 7; ++t) if (t < T){
      f32x4 St[7];
      #pragma unroll
      for (int tk = 0; tk < 7; ++tk) if (tk < T){
        St[tk] = MFMA_B16(kBf[tk], qAf[t], Z4);     // C [key][query] = S^T
        #pragma unroll
        for (int r = 0; r < 4; ++r){
          const int key = 16*tk + 4*q + r;
          if (key >= Lv) St[tk][r] = -1e30f;
        }
      }
      f32x4 mm = {-1e30f,-1e30f,-1e30f,-1e30f};
      #pragma unroll
      for (int tk = 0; tk < 7; ++tk) if (tk < T){
        mm[0]=fmaxf(mm[0],St[tk][0]); mm[1]=fmaxf(mm[1],St[tk][1]);
        mm[2]=fmaxf(mm[2],St[tk][2]); mm[3]=fmaxf(mm[3],St[tk][3]);
      }
      float m = fmaxf(fmaxf(mm[0],mm[1]), fmaxf(mm[2],mm[3]));
      m = fmaxf(m, __shfl_xor(m, 16));
      m = fmaxf(m, __shfl_xor(m, 32));
      f32x4 ss = Z4;
      #pragma unroll
      for (int tk = 0; tk < 7; ++tk) if (tk < T){
        #pragma unroll
        for (int r = 0; r < 4; ++r){
          float e = __expf(St[tk][r] - m);
          St[tk][r] = e; ss[r] += e;
        }
      }
      float sum = (ss[0]+ss[1]) + (ss[2]+ss[3]);
      sum += __shfl_xor(sum, 16);
      sum += __shfl_xor(sum, 32);
      const float inv = 1.0f / sum;
      #pragma unroll
      for (int tk = 0; tk < 7; ++tk) if (tk < T){
        short4v p4;
        #pragma unroll
        for (int r = 0; r < 4; ++r) p4[r] = (short)f2bf(St[tk][r] * inv);
        *(short4v*)&Pb[c*PSTR2 + 16*tk + 4*q] = p4;
      }
      f32x4 o = Z4;
      #pragma unroll
      for (int u = 0; u < 4; ++u) if (u < ((T+1)>>1)){
        const short8 ap = *(const short8*)&Pb[c*PSTR2 + 32*u + q*8];
        o = MFMA_B16(ap, vBf[u], o);
      }
      short4v ob;
      #pragma unroll
      for (int r = 0; r < 4; ++r) ob[r] = (short)f2bf(o[r]);
      of[t] = ob;
    }

    __syncthreads();   // all waves done with sF reads and P strips
    #pragma unroll
    for (int t = 0; t < 7; ++t) if (t < T){
      #pragma unroll
      for (int r = 0; r < 4; ++r)
        sF[(16*t + 4*q + r)*STR + h*16 + c] = (unsigned short)of[t][r];
    }
    __syncthreads();   // O complete

    // ---- out projection: wave handles tile t = wv8 (waves 0..T-1 active)
    {
      const int t = wv8;
      if (t < T){
        float bo_r[8];
        #pragma unroll
        for (int ct = 0; ct < 8; ++ct) bo_r[ct] = opb[ct*16 + c];
        f32x4 acc[8];
        #pragma unroll
        for (int ct = 0; ct < 8; ++ct) acc[ct] = Z4;
        #pragma unroll
        for (int p = 0; p < 4; ++p){
          const short8 ao = *(const short8*)&sF[(16*t + c)*STR + p*32 + q*8];
          #pragma unroll
          for (int ct = 0; ct < 8; ++ct){
            const short8 bw = *(const short8*)&wout[(ct*16 + c)*128 + p*32 + q*8];
            acc[ct] = MFMA_B16(ao, bw, acc[ct]);
          }
        }
        #pragma unroll
        for (int r = 0; r < 4; ++r){
          const int l = 16*t + 4*q + r;
          if (l < Lv){
            const int tok = inds2[ibase + l];
            float* orow = out + (long)tok*128;
            #pragma unroll
            for (int ct = 0; ct < 8; ++ct)
              orow[ct*16 + c] = acc[ct][r] + bo_r[ct];
          }
        }
      }
    }
  } else {
    // ============================ group1 path ============================
    // (R12 body verbatim; uses first 76800 B of LDS)
    const int wv8 = tid >> 6;                  // 0..7
    const int wh  = wv8 >> 2;                  // window half 0/1
    const int wv  = wv8 & 3;                   // wave within half
    const int lane = tid & 63, c = lane & 15, q = lane >> 4;

    unsigned short* base = smem + wh*HALF3;
    unsigned short* sQK = base;                     // [48][STR]
    unsigned short* sF  = base + 48*STR;            // [48][STR], O later
    unsigned short* sPb = base + 2*48*STR;          // 4 x [16][PSTR3]
    unsigned short* sTs = sPb + 4*16*PSTR3;         // 4 x [16][STRT3]

    const int w = (b - 1024)*2 + wh;
    const int LW = 36;
    const int Lv = wh ? 18 : 36;
    const int T  = wh ? 2 : 3;
    const long ibase = (long)w * LW;

    {
      const int ltid = tid & 255;
      const int rg = ltid >> 4, ch = ltid & 15;
      #pragma unroll
      for (int s = 0; s < TT3; ++s){
        if (s < T){
          const int row = s*16 + rg;
          short8 fv = Z8, qv = Z8;
          if (row < Lv){
            const int tok = inds1[ibase + row];
            const float* fr = feat + (long)tok*128 + ch*8;
            const float* pr = pos1 + (ibase + row)*128 + ch*8;
            f32x4 f0 = *(const f32x4*)fr, f1 = *(const f32x4*)(fr+4);
            f32x4 p0 = *(const f32x4*)pr, p1 = *(const f32x4*)(pr+4);
            fv = pack8(f0, f1); qv = pack8(f0+p0, f1+p1);
          }
          *(short8*)&sF [row*STR + ch*8] = fv;
          *(short8*)&sQK[row*STR + ch*8] = qv;
        }
      }
    }
    __syncthreads();

    unsigned short* Pb = sPb + wv*16*PSTR3;
    unsigned short* Ts = sTs + wv*16*STRT3;
    short4v of[2][TT3];

    #pragma unroll
    for (int hh = 0; hh < 2; ++hh){
      const int h = wv*2 + hh;
      short8 bQ[4], bK[4], bV[4];
      const unsigned short* wr = wqkv + (h*16 + c)*128 + q*8;
      #pragma unroll
      for (int kk = 0; kk < 4; ++kk){
        bQ[kk] = *(const short8*)(wr + kk*32);
        bK[kk] = *(const short8*)(wr + kk*32 + 128*128);
        bV[kk] = *(const short8*)(wr + kk*32 + 2*128*128);
      }
      float bq_r[4], bk_r[4];
      #pragma unroll
      for (int r = 0; r < 4; ++r){
        bq_r[r] = ipb[h*16 + 4*q + r];
        bk_r[r] = ipb[128 + h*16 + 4*q + r];
      }
      const float bv_c = ipb[256 + h*16 + c];

      short8 qAf[TT3], kBf[TT3];

      #pragma unroll
      for (int t = 0; t < TT3; ++t) if (t < T){
        f32x4 qt = Z4, kt = Z4, vt = Z4;
        #pragma unroll
        for (int kk = 0; kk < 4; ++kk){
          const short8 aQ = *(const short8*)&sQK[(16*t + c)*STR + kk*32 + q*8];
          const short8 aF = *(const short8*)&sF [(16*t + c)*STR + kk*32 + q*8];
          qt = MFMA_B16(bQ[kk], aQ, qt);
          kt = MFMA_B16(bK[kk], aQ, kt);
          vt = MFMA_B16(aF, bV[kk], vt);
        }
        #pragma unroll
        for (int r = 0; r < 4; ++r){
          qt[r] = (qt[r] + bq_r[r]) * 0.25f;
          kt[r] += bk_r[r];
          const int key = 16*t + 4*q + r;
          vt[r] = (key < Lv) ? (vt[r] + bv_c) : 0.f;
        }
        *(short4v*)&Pb[c*PSTR3 + 16*t + 4*q]   = pack4(vt);
        *(short4v*)&Ts[c*STRT3 + 4*q]          = pack4(qt);
        *(short4v*)&Pb[c*PSTR3 + KOFF3 + 4*q]  = pack4(kt);
        const short8 qf = *(const short8*)&Ts[c*STRT3 + q*8];
        const short8 kf = *(const short8*)&Pb[c*PSTR3 + KOFF3 + q*8];
        qAf[t] = (q < 2) ? qf : Z8;
        kBf[t] = (q < 2) ? kf : Z8;
      }
      {
        const short4v z4 = {0,0,0,0};
        *(short4v*)&Pb[c*PSTR3 + KOFF3 + 4*q] = z4;
      }

      short8 vBf[2];
      #pragma unroll
      for (int u = 0; u < 2; ++u) if (u < ((T+1)>>1))
        vBf[u] = *(const short8*)&Pb[c*PSTR3 + 32*u + q*8];

      #pragma unroll
      for (int t = 0; t < TT3; ++t) if (t < T){
        f32x4 St[TT3];
        #pragma unroll
        for (int tk = 0; tk < TT3; ++tk) if (tk < T){
          St[tk] = MFMA_B16(kBf[tk], qAf[t], Z4);     // C [key][query] = S^T
          #pragma unroll
          for (int r = 0; r < 4; ++r){
            const int key = 16*tk + 4*q + r;
            if (key >= Lv) St[tk][r] = -1e30f;
          }
        }
        f32x4 mm = {-1e30f,-1e30f,-1e30f,-1e30f};
        #pragma unroll
        for (int tk = 0; tk < TT3; ++tk) if (tk < T){
          mm[0]=fmaxf(mm[0],St[tk][0]); mm[1]=fmaxf(mm[1],St[tk][1]);
          mm[2]=fmaxf(mm[2],St[tk][2]); mm[3]=fmaxf(mm[3],St[tk][3]);
        }
        float m = fmaxf(fmaxf(mm[0],mm[1]), fmaxf(mm[2],mm[3]));
        m = fmaxf(m, __shfl_xor(m, 16));
        m = fmaxf(m, __shfl_xor(m, 32));
        f32x4 ss = Z4;
        #pragma unroll
        for (int tk = 0; tk < TT3; ++tk) if (tk < T){
          #pragma unroll
          for (int r = 0; r < 4; ++r){
            float e = __expf(St[tk][r] - m);
            St[tk][r] = e; ss[r] += e;
          }
        }
        float sum = (ss[0]+ss[1]) + (ss[2]+ss[3]);
        sum += __shfl_xor(sum, 16);
        sum += __shfl_xor(sum, 32);
        const float inv = 1.0f / sum;
        #pragma unroll
        for (int tk = 0; tk < TT3; ++tk) if (tk < T){
          short4v p4;
          #pragma unroll
          for (int r = 0; r < 4; ++r) p4[r] = (short)f2bf(St[tk][r] * inv);
          *(short4v*)&Pb[c*PSTR3 + 16*tk + 4*q] = p4;
        }
        f32x4 o = Z4;
        #pragma unroll
        for (int u = 0; u < 2; ++u) if (u < ((T+1)>>1)){
          const short8 ap = *(const short8*)&Pb[c*PSTR3 + 32*u + q*8];
          o = MFMA_B16(ap, vBf[u], o);
        }
        short4v ob;
        #pragma unroll
        for (int r = 0; r < 4; ++r) ob[r] = (short)f2bf(o[r]);
        of[hh][t] = ob;
      }
    } // hh

    __syncthreads();   // all waves done reading sQK/sF (both halves)
    #pragma unroll
    for (int hh = 0; hh < 2; ++hh){
      const int h = wv*2 + hh;
      #pragma unroll
      for (int t = 0; t < TT3; ++t) if (t < T){
        #pragma unroll
        for (int r = 0; r < 4; ++r)
          sF[(16*t + 4*q + r)*STR + h*16 + c] = (unsigned short)of[hh][t][r];
      }
    }
    __syncthreads();   // O complete

    // ---- out projection: wave handles query tile wv of its window
    {
      const int t = wv;
      if (t < T){
        float bo_r[8];
        #pragma unroll
        for (int ct = 0; ct < 8; ++ct) bo_r[ct] = opb[ct*16 + c];
        f32x4 acc[8];
        #pragma unroll
        for (int ct = 0; ct < 8; ++ct) acc[ct] = Z4;
        #pragma unroll
        for (int p = 0; p < 4; ++p){
          const short8 ao = *(const short8*)&sF[(16*t + c)*STR + p*32 + q*8];
          #pragma unroll
          for (int ct = 0; ct < 8; ++ct){
            const short8 bw = *(const short8*)&wout[(ct*16 + c)*128 + p*32 + q*8];
            acc[ct] = MFMA_B16(ao, bw, acc[ct]);
          }
        }
        #pragma unroll
        for (int r = 0; r < 4; ++r){
          const int l = 16*t + 4*q + r;
          if (l < Lv){
            const int tok = inds1[ibase + l];
            float* orow = out + (long)tok*128;
            #pragma unroll
            for (int ct = 0; ct < 8; ++ct)
              orow[ct*16 + c] = acc[ct][r] + bo_r[ct];
          }
        }
      }
    }
  }
}

extern "C" void kernel_launch(void* const* d_in, const int* in_sizes, int n_in,
                              void* d_out, int out_size, void* d_ws, size_t ws_size,
                              hipStream_t stream) {
  const float* feat = (const float*)d_in[0];
  const float* pos1 = (const float*)d_in[1];
  const float* pos2 = (const float*)d_in[2];
  const float* ipw  = (const float*)d_in[3];
  const float* ipb  = (const float*)d_in[4];
  const float* opw  = (const float*)d_in[5];
  const float* opb  = (const float*)d_in[6];
  const int*   inds1 = (const int*)d_in[7];
  const int*   inds2 = (const int*)d_in[8];
  float* out = (float*)d_out;
  unsigned short* wbf = (unsigned short*)d_ws;   // 384*128 + 128*128 bf16
  unsigned short* wob = wbf + 384*128;

  prep_w<<<dim3(256), dim3(256), 0, stream>>>(ipw, opw, wbf);

  // merged: LDS request = g1 layout = 2*HALF3*2 = 76800 B -> 2 blocks/CU.
  // g2 path uses 2*112*STR*2 + 8*16*STRT2*2 + 16*PSTR2*2 = 71424 B of it.
  const int lds = 2*HALF3*2;
  hipFuncSetAttribute((const void*)fused_all,
                      hipFuncAttributeMaxDynamicSharedMemorySize, lds);
  fused_all<<<dim3(1024 + 2048), dim3(512), lds, stream>>>(
      feat, pos1, pos2, inds1, inds2, wbf, wob, ipb, opb, out);
}